// Round 3
// baseline (8392.160 us; speedup 1.0000x reference)
//
#include <hip/hip_runtime.h>
#include <hip/hip_bf16.h>

#define B_ 512
#define T_ 256
#define F_ 128
#define H_ 1024
#define KD 1152          // F_ + H_
#define NBLK 256
#define HPBUF 524288     // elems per hpack buffer: 32 hseg * 512 rows * 32
#define WP_NB 147456     // elems per nb slice of packed W: 36 c32 * 8 frags * 512
#define SBUF 16384       // shorts per stage buffer: 4 kg * 1 c32 * 8 frags * 512 (32 KiB)

typedef __attribute__((ext_vector_type(8))) short short8;
typedef __attribute__((ext_vector_type(4))) float float4v;

#define MFMA(a,b,c) __builtin_amdgcn_mfma_f32_16x16x32_bf16(a,b,c,0,0,0)

__device__ __forceinline__ unsigned short f2bf(float x){
  unsigned u = __float_as_uint(x);
  unsigned r = (u + 0x7fffu + ((u >> 16) & 1u)) >> 16;
  return (unsigned short)r;
}
__device__ __forceinline__ float bf2f(unsigned short b){
  return __uint_as_float(((unsigned)b) << 16);
}
__device__ __forceinline__ float sigf(float x){ return 1.f / (1.f + __expf(-x)); }
__device__ __forceinline__ float tanh_f(float x){
  float e = __expf(2.f * x);
  return (e - 1.f) / (e + 1.f);
}

// async global->LDS copy, 16B per lane. lbase must be wave-uniform; HW adds lane*16.
__device__ __forceinline__ void cp16(const unsigned short* g, unsigned short* lbase, int lane){
#if defined(__has_builtin) && __has_builtin(__builtin_amdgcn_global_load_lds)
  __builtin_amdgcn_global_load_lds((const __attribute__((address_space(1))) unsigned int*)g,
                                   (__attribute__((address_space(3))) unsigned int*)lbase, 16, 0, 0);
#else
  *(short8*)(lbase + lane * 8) = *(const short8*)g;
#endif
}

// ---------------- W pre-pack: split hi/lo bf16 and lay out in MFMA B-fragment order -------------
// wp[nb][c32][frag 0..7][lane*8+j], frag 0..3 = hi for ntile(gate) 0..3, 4..7 = lo.
__global__ void __launch_bounds__(256) pack_w(const float* __restrict__ Wl, unsigned short* __restrict__ wp){
  int bid = blockIdx.x;                 // 64*36
  int nb = bid / 36, c32 = bid % 36;
  int tid = threadIdx.x;
  int nt = tid >> 6, lane = tid & 63;
  int u = lane & 15, q = lane >> 4;
  int gcol = nt * H_ + nb * 16 + u;     // ntile == gate
  int k0 = c32 * 32 + q * 8;
  short8 hi, lo;
#pragma unroll
  for (int j = 0; j < 8; j++){
    float x = Wl[(size_t)(k0 + j) * 4096 + gcol];
    unsigned short hb = f2bf(x);
    hi[j] = (short)hb;
    lo[j] = (short)f2bf(x - bf2f(hb));
  }
  size_t base = (size_t)(nb * 36 + c32) * 8;
  *(short8*)&wp[(base + nt) * 512 + lane * 8] = hi;
  *(short8*)&wp[(base + 4 + nt) * 512 + lane * 8] = lo;
}

// ---------------- persistent cooperative LSTM kernel ----------------
// 16 waves: wr = w&3 picks 32-row group, kg = w>>2 picks K quarter.
// kg q: x c32 {q} + h c32 {4+q*8 .. 4+q*8+7}. Phase stages 1 c32 per kg (32 KiB, dbuf).
__device__ __forceinline__ void stage_phase(const unsigned short* __restrict__ wpnb,
                                            unsigned short* dst, int p, int w, int lane){
#pragma unroll
  for (int i = 0; i < 2; i++){
    int idx = w * 2 + i;                 // 32 chunks of 1 KiB
    int kgs = idx >> 3, frag = idx & 7;
    int c32 = (p == 0) ? kgs : (4 + kgs * 8 + (p - 1));
    cp16(wpnb + (size_t)(c32 * 8 + frag) * 512 + lane * 8,
         dst + (kgs * 8 + frag) * 512, lane);
  }
}

struct Areg { short8 h[2]; short8 l[2]; };   // [m]

__device__ __forceinline__ void issueA(const unsigned short* __restrict__ rh,
                                       const unsigned short* __restrict__ rl,
                                       int aoff0, int c32, Areg& d){
  int off = (c32 - 4) * 16384 + aoff0;
  d.h[0] = *(const short8*)(rh + off);
  d.h[1] = *(const short8*)(rh + off + 512);
  d.l[0] = *(const short8*)(rl + off);
  d.l[1] = *(const short8*)(rl + off + 512);
}

__device__ __forceinline__ void issueXF(const float* __restrict__ xb0, int tn, int kg,
                                        float4v (&xf)[2][2]){
#pragma unroll
  for (int m = 0; m < 2; m++){
    const float* px = xb0 + (size_t)m * 16 * (T_ * F_) + tn * F_ + kg * 32;
    xf[m][0] = *(const float4v*)px;
    xf[m][1] = *(const float4v*)(px + 4);
  }
}

__device__ __forceinline__ void loadB(const unsigned short* fb, short8 (&bh)[4], short8 (&bl)[4]){
#pragma unroll
  for (int nt = 0; nt < 4; nt++){
    bh[nt] = *(const short8*)(fb + nt * 512);
    bl[nt] = *(const short8*)(fb + (4 + nt) * 512);
  }
}

__device__ __forceinline__ void mfma3(const short8 (&ah)[2], const short8 (&al)[2],
                                      const short8 (&bh)[4], const short8 (&bl)[4],
                                      float4v (&acc)[2][4]){
#pragma unroll
  for (int nt = 0; nt < 4; nt++){
    acc[0][nt] = MFMA(ah[0], bh[nt], acc[0][nt]);
    acc[1][nt] = MFMA(ah[1], bh[nt], acc[1][nt]);
  }
#pragma unroll
  for (int nt = 0; nt < 4; nt++){
    acc[0][nt] = MFMA(ah[0], bl[nt], acc[0][nt]);
    acc[1][nt] = MFMA(ah[1], bl[nt], acc[1][nt]);
  }
#pragma unroll
  for (int nt = 0; nt < 4; nt++){
    acc[0][nt] = MFMA(al[0], bh[nt], acc[0][nt]);
    acc[1][nt] = MFMA(al[1], bh[nt], acc[1][nt]);
  }
}

__device__ __forceinline__ void computeH(const unsigned short* sbl, const Areg& a, float4v (&acc)[2][4]){
  short8 bh[4], bl[4];
  loadB(sbl, bh, bl);
  mfma3(a.h, a.l, bh, bl, acc);
}

__device__ __forceinline__ void computeX(const float4v (&xf)[2][2], const unsigned short* sbl,
                                         float4v (&acc)[2][4]){
  short8 ah[2], al[2];
#pragma unroll
  for (int m = 0; m < 2; m++){
    short8 hi8, lo8;
#pragma unroll
    for (int j = 0; j < 8; j++){
      float x = (j < 4) ? xf[m][0][j] : xf[m][1][j - 4];
      unsigned short hb = f2bf(x);
      hi8[j] = (short)hb;
      lo8[j] = (short)f2bf(x - bf2f(hb));
    }
    ah[m] = hi8; al[m] = lo8;
  }
  short8 bh[4], bl[4];
  loadB(sbl, bh, bl);
  mfma3(ah, al, bh, bl, acc);
}

__global__ void __launch_bounds__(1024, 1) lstm_coop(
    const float* __restrict__ hist, const float* __restrict__ blstm,
    const unsigned short* __restrict__ wp,
    unsigned short* __restrict__ hp_hi, unsigned short* __restrict__ hp_lo,
    float* __restrict__ cfin, unsigned* __restrict__ flags){
  __shared__ __align__(16) unsigned short stage[2 * SBUF];  // 64 KiB double buffer
  __shared__ __align__(16) float red[16384];                // 64 KiB K-partial exchange

  int b = blockIdx.x;
  int xcd = b & 7, jj = b >> 3;
  int nb = xcd * 8 + (jj & 7);          // XCD-local nb for L2 locality
  int mb = jj >> 3;                     // == b >> 6 ; barrier group
  int tid = threadIdx.x;
  int w = tid >> 6, lane = tid & 63;
  int kg = w >> 2, wr = w & 3;          // 16 waves: 4 wr x 4 kg
  int u = lane & 15, q = lane >> 4;
  int rbase = mb * 128 + wr * 32;

  const unsigned short* wp_nb = wp + (size_t)nb * WP_NB;

  float bias_v[4];
#pragma unroll
  for (int nt = 0; nt < 4; nt++) bias_v[nt] = blstm[nt * H_ + nb * 16 + u];

  int rowA0 = rbase + u;                       // A-fragment rows (m=0 tile)
  int aoff0 = rowA0 * 32 + q * 8;              // elems; + hseg*16384 (+512 for m=1)
  const float* xb0 = hist + (size_t)rowA0 * (T_ * F_) + q * 8;

  // gate-finalizer role: kg0 -> m=0 rows, kg2 -> m=1 rows (kg1/kg3 only hand partials)
  int mh = (kg == 2) ? 1 : 0;
  int hsegw = nb >> 1;
  int kin = (nb & 1) * 16 + u;
  int howm = hsegw * 16384 + (rbase + 16 * mh + q * 4) * 32 + kin;
  int rowc = rbase + 16 * mh + q * 4;

  float cst[4];
#pragma unroll
  for (int r = 0; r < 4; r++) cst[r] = 0.f;

  int c0k = 4 + kg * 8;

  // prologue: stage phase 0 of t=0, prefetch x(t=0)
  stage_phase(wp_nb, stage, 0, w, lane);
  Areg A0, A1;
  float4v xf[2][2];
  issueXF(xb0, 0, kg, xf);
  int cb = 0;

#pragma unroll 1
  for (int t = 0; t < T_; ++t){
    int bufr = t & 1, bufw = bufr ^ 1;
    const unsigned short* rh = hp_hi + bufr * HPBUF;
    const unsigned short* rl = hp_lo + bufr * HPBUF;

    float4v acc[2][4];
#pragma unroll
    for (int m = 0; m < 2; m++)
#pragma unroll
      for (int nt = 0; nt < 4; nt++) acc[m][nt] = (float4v){0.f, 0.f, 0.f, 0.f};

    // ---- phase 0: x columns (no h dependency); wave0 polls group barrier meanwhile ----
    __syncthreads();                                         // stage(0)+xf drained
    stage_phase(wp_nb, stage + (cb ^ 1) * SBUF, 1, w, lane);
    if (t && w == 0){
      const unsigned* f = flags + t * NBLK + (mb << 6);      // own 64-block group
      int ok;
      do {
        ok = (__hip_atomic_load(&f[lane], __ATOMIC_RELAXED, __HIP_MEMORY_SCOPE_AGENT) != 0u);
        if (__all(ok)) break;
        __builtin_amdgcn_s_sleep(2);
      } while (1);
      __builtin_amdgcn_fence(__ATOMIC_ACQUIRE, "agent");     // L2 inv before any h(t-1) read
    }
    computeX(xf, stage + cb * SBUF + kg * 4096 + lane * 8, acc);
    if (t) __syncthreads();                                  // order all waves after fence
    issueA(rh, rl, aoff0, c0k, A0);                          // prefetch A(1)
    cb ^= 1;

    // ---- phases 1..8: h columns, A prefetched one phase ahead ----
#pragma unroll
    for (int pq = 0; pq < 4; pq++){
      const int p1 = 1 + 2 * pq, p2 = 2 + 2 * pq;
      __syncthreads();                                       // stage(p1)+A(p1) drained
      stage_phase(wp_nb, stage + (cb ^ 1) * SBUF, p1 + 1, w, lane);
      issueA(rh, rl, aoff0, c0k + p1, A1);                   // A(p1+1)
      computeH(stage + cb * SBUF + kg * 4096 + lane * 8, A0, acc);
      cb ^= 1;
      __syncthreads();                                       // stage(p2)+A(p2) drained
      stage_phase(wp_nb, stage + (cb ^ 1) * SBUF, (p2 < 8) ? p2 + 1 : 0, w, lane);
      if (p2 < 8) issueA(rh, rl, aoff0, c0k + p2, A0);       // A(p2+1)
      else        issueXF(xb0, (t + 1 < T_) ? t + 1 : t, kg, xf);  // x(t+1)
      computeH(stage + cb * SBUF + kg * 4096 + lane * 8, A1, acc);
      cb ^= 1;
    }

    // ---- 4-way K reduction: kg1->kg0, kg3->kg2, then cross-swap m halves ----
    // round A: odd kgs dump both m partials (no sync needed before: own acc, own region)
    if (kg & 1){
      int base = ((kg >> 1) * 4 + wr) * 2048;
#pragma unroll
      for (int m = 0; m < 2; m++)
#pragma unroll
        for (int nt = 0; nt < 4; nt++)
          *(float4v*)&red[base + (m * 4 + nt) * 256 + lane * 4] = acc[m][nt];
    }
    __syncthreads();
    if (!(kg & 1)){
      int base = ((kg >> 1) * 4 + wr) * 2048;
      int mo = mh ^ 1;                       // the m-half this wave hands off
#pragma unroll
      for (int m = 0; m < 2; m++)
#pragma unroll
        for (int nt = 0; nt < 4; nt++)
          acc[m][nt] += *(const float4v*)&red[base + (m * 4 + nt) * 256 + lane * 4];
      // write back the non-finalized half into the slots just read (same-lane, in-order safe)
#pragma unroll
      for (int nt = 0; nt < 4; nt++)
        *(float4v*)&red[base + (mo * 4 + nt) * 256 + lane * 4] = acc[mo][nt];
    }
    __syncthreads();

    if (!(kg & 1)){
      int obase = (((kg >> 1) ^ 1) * 4 + wr) * 2048;         // counterpart's region
      float4v am[4];
#pragma unroll
      for (int nt = 0; nt < 4; nt++)
        am[nt] = acc[mh][nt] + *(const float4v*)&red[obase + (mh * 4 + nt) * 256 + lane * 4];

      unsigned short* wh = hp_hi + bufw * HPBUF;
      unsigned short* wl2 = hp_lo + bufw * HPBUF;
#pragma unroll
      for (int r = 0; r < 4; r++){
        float zi = am[0][r] + bias_v[0];
        float zj = am[1][r] + bias_v[1];
        float zf = am[2][r] + bias_v[2];
        float zo = am[3][r] + bias_v[3];
        float co = cst[r];
        float cn = sigf(zf + 1.f) * co + sigf(zi) * tanh_f(zj);
        float hn = sigf(zo) * tanh_f(cn);
        cst[r] = cn;
        int off = howm + r * 32;
        unsigned short hb = f2bf(hn);
        wh[off] = hb;
        wl2[off] = f2bf(hn - bf2f(hb));
        if (t == T_ - 1)
          cfin[(size_t)(rowc + r) * H_ + nb * 16 + u] = cn;
      }
    }
    __syncthreads();                           // drains vmcnt: h stores complete at L2
    if (tid == 0 && t + 1 < T_){
      __builtin_amdgcn_fence(__ATOMIC_RELEASE, "agent");   // push h to coherence point
      __hip_atomic_store(&flags[(t + 1) * NBLK + b], 1u, __ATOMIC_RELAXED,
                         __HIP_MEMORY_SCOPE_AGENT);        // arrive for step t+1
    }
  }
}

// ---------------- head ----------------
__global__ void __launch_bounds__(256) build_feat(const float* __restrict__ head,
    const float* __restrict__ cfin, const unsigned short* __restrict__ hh,
    const unsigned short* __restrict__ hl, float* __restrict__ feat){
  int row = blockIdx.x;
  for (int kp = threadIdx.x; kp < 2080; kp += 256){
    float v;
    if (kp < 2) v = head[row * 3 + 1 + kp];
    else if (kp < 1026) v = cfin[(size_t)row * H_ + (kp - 2)];
    else if (kp < 2050){
      int n = kp - 1026;
      int off = (n >> 5) * 16384 + row * 32 + ((n & 31) >> 3) * 8 + (n & 7);
      v = bf2f(hh[off]) + bf2f(hl[off]);
    } else v = 0.f;
    feat[(size_t)row * 2080 + kp] = v;
  }
}

__global__ void __launch_bounds__(256) mlp_head(const float* __restrict__ feat,
    const float* __restrict__ W3, const float* __restrict__ b3,
    const float* __restrict__ W4, const float* __restrict__ b4,
    const float* __restrict__ W5, const float* __restrict__ b5,
    const float* __restrict__ W6, const float* __restrict__ b6,
    float* __restrict__ G){
  __shared__ float ftile[64][33];
  int bid = blockIdx.x;
  int mb = bid >> 5, nbk = bid & 31;
  int tid = threadIdx.x;
  int tr = tid >> 4, tc = tid & 15;
  int mat = nbk >> 3;
  const float* Wm = (mat == 0) ? W3 : (mat == 1) ? W4 : (mat == 2) ? W5 : W6;
  const float* bm = (mat == 0) ? b3 : (mat == 1) ? b4 : (mat == 2) ? b5 : b6;
  int lc = (nbk & 7) * 64 + tc * 4;
  int r0 = mb * 64;
  float racc[4][4] = {};
  for (int k0 = 0; k0 < 2080; k0 += 32){
    int rr = tid >> 3, cc = (tid & 7) * 4;
    float4v v0 = *(const float4v*)&feat[(size_t)(r0 + rr) * 2080 + k0 + cc];
    float4v v1 = *(const float4v*)&feat[(size_t)(r0 + rr + 32) * 2080 + k0 + cc];
#pragma unroll
    for (int i = 0; i < 4; i++){ ftile[rr][cc + i] = v0[i]; ftile[rr + 32][cc + i] = v1[i]; }
    __syncthreads();
#pragma unroll 4
    for (int kk = 0; kk < 32; kk++){
      int k = k0 + kk;
      float4v bv = (float4v){0.f, 0.f, 0.f, 0.f};
      if (k < 2050) bv = *(const float4v*)&Wm[(size_t)k * 512 + lc];
      float a0 = ftile[tr * 4 + 0][kk];
      float a1 = ftile[tr * 4 + 1][kk];
      float a2 = ftile[tr * 4 + 2][kk];
      float a3 = ftile[tr * 4 + 3][kk];
#pragma unroll
      for (int j = 0; j < 4; j++){
        racc[0][j] += a0 * bv[j]; racc[1][j] += a1 * bv[j];
        racc[2][j] += a2 * bv[j]; racc[3][j] += a3 * bv[j];
      }
    }
    __syncthreads();
  }
#pragma unroll
  for (int i = 0; i < 4; i++){
    float4v v;
#pragma unroll
    for (int j = 0; j < 4; j++){
      float x = racc[i][j] + bm[lc + j];
      v[j] = fmaxf(x, 0.f);
    }
    *(float4v*)&G[(size_t)(r0 + tr * 4 + i) * 2048 + nbk * 64 + tc * 4] = v;
  }
}

__global__ void __launch_bounds__(256) final_q(const float* __restrict__ G,
    const float* __restrict__ head, const float* __restrict__ tq, const int* __restrict__ act,
    const float* __restrict__ Wsv, const float* __restrict__ bsv,
    const float* __restrict__ Wbv, const float* __restrict__ bbv,
    const float* __restrict__ Wsh, const float* __restrict__ bsh,
    const float* __restrict__ Wbh, const float* __restrict__ bbh,
    float* __restrict__ out){
  int row = blockIdx.x, tid = threadIdx.x;
  const float* g = G + (size_t)row * 2048;
  float s0=0,s1=0,s2=0,s3=0,s4=0,s5=0;
  for (int k = tid; k < 512; k += 256){
    float vlp = g[k], qlp = g[512 + k], vle = g[1024 + k], qle = g[1536 + k];
    s0 += vlp * Wsv[k];
    s1 += qlp * Wsh[2 * k];  s2 += qlp * Wsh[2 * k + 1];
    s3 += vle * Wbv[k];
    s4 += qle * Wbh[2 * k];  s5 += qle * Wbh[2 * k + 1];
  }
#pragma unroll
  for (int off = 32; off; off >>= 1){
    s0 += __shfl_down(s0, off); s1 += __shfl_down(s1, off); s2 += __shfl_down(s2, off);
    s3 += __shfl_down(s3, off); s4 += __shfl_down(s4, off); s5 += __shfl_down(s5, off);
  }
  __shared__ float red[4][6];
  int w = tid >> 6, lane = tid & 63;
  if (lane == 0){ red[w][0]=s0; red[w][1]=s1; red[w][2]=s2; red[w][3]=s3; red[w][4]=s4; red[w][5]=s5; }
  __syncthreads();
  if (tid == 0){
    float r[6];
#pragma unroll
    for (int i = 0; i < 6; i++) r[i] = red[0][i] + red[1][i] + red[2][i] + red[3][i];
    float pa0 = r[1] + bsh[0], pa1 = r[2] + bsh[1];
    float pv  = r[0] + bsv[0];
    float pm  = 0.5f * (pa0 + pa1);
    float pQ0 = pa0 - pm + pv, pQ1 = pa1 - pm + pv;
    float ea0 = r[4] + bbh[0], ea1 = r[5] + bbh[1];
    float ev  = r[3] + bbv[0];
    float em  = 0.5f * (ea0 + ea1);
    float eQ0 = ea0 - em + ev, eQ1 = ea1 - em + ev;
    bool isp = (head[row * 3] != 0.f);
    float Q0 = isp ? pQ0 : eQ0;
    float Q1 = isp ? eQ1 : pQ1;   // mask col1 = (1-is_pos)!=0
    float gr = (Q1 > Q0) ? 1.f : 0.f;
    int a = act[row];
    float iv = (a == 0) ? Q0 : Q1;
    float d = tq[row] - iv;
    atomicAdd(out, d * d * (1.f / 512.f));
    out[1 + 2 * row] = Q0;
    out[2 + 2 * row] = Q1;
    out[1025 + row] = gr;
  }
}

// ---------------- launch ----------------
extern "C" void kernel_launch(void* const* d_in, const int* in_sizes, int n_in,
                              void* d_out, int out_size, void* d_ws, size_t ws_size,
                              hipStream_t stream){
  const float* hist = (const float*)d_in[0];
  const float* head = (const float*)d_in[1];
  const float* tq   = (const float*)d_in[2];
  const int*   act  = (const int*)d_in[3];
  const float* Wl   = (const float*)d_in[4];
  const float* bl   = (const float*)d_in[5];
  const float* W3 = (const float*)d_in[6];  const float* b3 = (const float*)d_in[7];
  const float* W4 = (const float*)d_in[8];  const float* b4 = (const float*)d_in[9];
  const float* W5 = (const float*)d_in[10]; const float* b5 = (const float*)d_in[11];
  const float* W6 = (const float*)d_in[12]; const float* b6 = (const float*)d_in[13];
  const float* Wsv = (const float*)d_in[14]; const float* bsv = (const float*)d_in[15];
  const float* Wbv = (const float*)d_in[16]; const float* bbv = (const float*)d_in[17];
  const float* Wsh = (const float*)d_in[18]; const float* bsh = (const float*)d_in[19];
  const float* Wbh = (const float*)d_in[20]; const float* bbh = (const float*)d_in[21];
  float* out = (float*)d_out;

  char* ws = (char*)d_ws;
  unsigned* flags      = (unsigned*)ws;                       // 256*256*4 = 262144
  unsigned short* hp_hi = (unsigned short*)(ws + 262144);      // 2 MiB
  unsigned short* hp_lo = (unsigned short*)(ws + 2359296);     // 2 MiB
  unsigned short* wp    = (unsigned short*)(ws + 4456448);     // 18.87 MB
  float* cfin = (float*)(ws + 23330816);                       // 2 MiB
  float* feat = (float*)(ws + 25427968);                       // 4.26 MB
  float* G    = (float*)(ws + 29687808);                       // 4.19 MB -> total ~33.9 MB

  // zero barrier flags + both h double-buffers (h(-1) = 0)
  hipMemsetAsync(ws, 0, 4456448, stream);
  hipMemsetAsync(d_out, 0, sizeof(float), stream);             // loss accumulator

  pack_w<<<dim3(64 * 36), dim3(256), 0, stream>>>(Wl, wp);

  void* args[] = {(void*)&hist, (void*)&bl, (void*)&wp, (void*)&hp_hi,
                  (void*)&hp_lo, (void*)&cfin, (void*)&flags};
  hipLaunchCooperativeKernel((void*)lstm_coop, dim3(NBLK), dim3(1024), args, 0, stream);

  build_feat<<<dim3(512), dim3(256), 0, stream>>>(head, cfin, hp_hi, hp_lo, feat);
  mlp_head<<<dim3(256), dim3(256), 0, stream>>>(feat, W3, b3, W4, b4, W5, b5, W6, b6, G);
  final_q<<<dim3(512), dim3(256), 0, stream>>>(G, head, tq, act,
      Wsv, bsv, Wbv, bbv, Wsh, bsh, Wbh, bbh, out);
}

// Round 5
// 7711.835 us; speedup vs baseline: 1.0882x; 1.0882x over previous
//
#include <hip/hip_runtime.h>
#include <hip/hip_bf16.h>

#define B_ 512
#define T_ 256
#define F_ 128
#define H_ 1024
#define KD 1152          // F_ + H_
#define NBLK 256
#define HPBUF 524288     // elems per hpack buffer: 32 hseg * 512 rows * 32
#define WP_NB 147456     // elems per nb slice of packed W: 36 c32 * 8 frags * 512
#define SBUF 16384       // shorts per stage buffer: 2 kg * 2 c32 * 8 frags * 512 (32 KiB)

typedef __attribute__((ext_vector_type(8))) short short8;
typedef __attribute__((ext_vector_type(4))) float float4v;

#define MFMA(a,b,c) __builtin_amdgcn_mfma_f32_16x16x32_bf16(a,b,c,0,0,0)

__device__ __forceinline__ unsigned short f2bf(float x){
  unsigned u = __float_as_uint(x);
  unsigned r = (u + 0x7fffu + ((u >> 16) & 1u)) >> 16;
  return (unsigned short)r;
}
__device__ __forceinline__ float bf2f(unsigned short b){
  return __uint_as_float(((unsigned)b) << 16);
}
__device__ __forceinline__ float sigf(float x){ return 1.f / (1.f + __expf(-x)); }
__device__ __forceinline__ float tanh_f(float x){
  float e = __expf(2.f * x);
  return (e - 1.f) / (e + 1.f);
}

// ---- system-scope (point-of-coherence) h accessors: no L2 invalidate needed anywhere ----
__device__ __forceinline__ unsigned long long ld8_sys(const unsigned short* p){
  return __hip_atomic_load((const unsigned long long*)p, __ATOMIC_RELAXED,
                           __HIP_MEMORY_SCOPE_SYSTEM);
}
__device__ __forceinline__ short8 ld16_sys(const unsigned short* p){
  union { unsigned long long q[2]; short8 s; } u;
  u.q[0] = ld8_sys(p);
  u.q[1] = ld8_sys(p + 4);
  return u.s;
}
__device__ __forceinline__ void st2_sys(unsigned short* p, unsigned short v){
  __hip_atomic_store(p, v, __ATOMIC_RELAXED, __HIP_MEMORY_SCOPE_SYSTEM);
}

// async global->LDS copy, 16B per lane. lbase must be wave-uniform; HW adds lane*16.
__device__ __forceinline__ void cp16(const unsigned short* g, unsigned short* lbase, int lane){
#if defined(__has_builtin) && __has_builtin(__builtin_amdgcn_global_load_lds)
  __builtin_amdgcn_global_load_lds((const __attribute__((address_space(1))) unsigned int*)g,
                                   (__attribute__((address_space(3))) unsigned int*)lbase, 16, 0, 0);
#else
  *(short8*)(lbase + lane * 8) = *(const short8*)g;
#endif
}

// ---------------- W pre-pack: split hi/lo bf16 and lay out in MFMA B-fragment order -------------
// wp[nb][c32][frag 0..7][lane*8+j], frag 0..3 = hi for ntile(gate) 0..3, 4..7 = lo.
__global__ void __launch_bounds__(256) pack_w(const float* __restrict__ Wl, unsigned short* __restrict__ wp){
  int bid = blockIdx.x;                 // 64*36
  int nb = bid / 36, c32 = bid % 36;
  int tid = threadIdx.x;
  int nt = tid >> 6, lane = tid & 63;
  int u = lane & 15, q = lane >> 4;
  int gcol = nt * H_ + nb * 16 + u;     // ntile == gate
  int k0 = c32 * 32 + q * 8;
  short8 hi, lo;
#pragma unroll
  for (int j = 0; j < 8; j++){
    float x = Wl[(size_t)(k0 + j) * 4096 + gcol];
    unsigned short hb = f2bf(x);
    hi[j] = (short)hb;
    lo[j] = (short)f2bf(x - bf2f(hb));
  }
  size_t base = (size_t)(nb * 36 + c32) * 8;
  *(short8*)&wp[(base + nt) * 512 + lane * 8] = hi;
  *(short8*)&wp[(base + 4 + nt) * 512 + lane * 8] = lo;
}

// ---------------- persistent cooperative LSTM kernel ----------------
// 8 waves: wr = w&3 picks 32-row group, kg = w>>2 picks K-half.
// kg0: c32 {0,1} + h c32 4..19 ; kg1: c32 {2,3} + h c32 20..35.
// Phase p stages/computes 2 c32 per kg (32 KiB per phase, double-buffered).
__device__ __forceinline__ void stage_phase(const unsigned short* __restrict__ wpnb,
                                            unsigned short* dst, int p, int w, int lane){
#pragma unroll
  for (int i = 0; i < 4; i++){
    int idx = w * 4 + i;                 // 32 chunks of 1 KiB
    int kgs = idx >> 4, lc = (idx >> 3) & 1, frag = idx & 7;
    int c32 = (p == 0) ? (kgs * 2 + lc) : (4 + kgs * 16 + (p - 1) * 2 + lc);
    cp16(wpnb + (size_t)(c32 * 8 + frag) * 512 + lane * 8,
         dst + ((kgs * 2 + lc) * 8 + frag) * 512, lane);
  }
}

struct Areg { short8 h[2][2]; short8 l[2][2]; };   // [s][m]

__device__ __forceinline__ void issueA(const unsigned short* __restrict__ rh,
                                       const unsigned short* __restrict__ rl,
                                       int aoff0, int c0, Areg& d){
#pragma unroll
  for (int s = 0; s < 2; s++){
    int off = (c0 + s - 4) * 16384 + aoff0;
    d.h[s][0] = ld16_sys(rh + off);
    d.h[s][1] = ld16_sys(rh + off + 512);
    d.l[s][0] = ld16_sys(rl + off);
    d.l[s][1] = ld16_sys(rl + off + 512);
  }
}

__device__ __forceinline__ void issueXF(const float* __restrict__ xb0, int tn, int kg,
                                        float4v (&xf)[2][2][2]){
#pragma unroll
  for (int s = 0; s < 2; s++)
#pragma unroll
    for (int m = 0; m < 2; m++){
      const float* px = xb0 + (size_t)m * 16 * (T_ * F_) + tn * F_ + (kg * 2 + s) * 32;
      xf[s][m][0] = *(const float4v*)px;
      xf[s][m][1] = *(const float4v*)(px + 4);
    }
}

__device__ __forceinline__ void loadB(const unsigned short* fb, short8 (&bh)[4], short8 (&bl)[4]){
#pragma unroll
  for (int nt = 0; nt < 4; nt++){
    bh[nt] = *(const short8*)(fb + nt * 512);
    bl[nt] = *(const short8*)(fb + (4 + nt) * 512);
  }
}

__device__ __forceinline__ void mfma3(const short8 (&ah)[2], const short8 (&al)[2],
                                      const short8 (&bh)[4], const short8 (&bl)[4],
                                      float4v (&acc)[2][4]){
#pragma unroll
  for (int nt = 0; nt < 4; nt++){
    acc[0][nt] = MFMA(ah[0], bh[nt], acc[0][nt]);
    acc[1][nt] = MFMA(ah[1], bh[nt], acc[1][nt]);
  }
#pragma unroll
  for (int nt = 0; nt < 4; nt++){
    acc[0][nt] = MFMA(ah[0], bl[nt], acc[0][nt]);
    acc[1][nt] = MFMA(ah[1], bl[nt], acc[1][nt]);
  }
#pragma unroll
  for (int nt = 0; nt < 4; nt++){
    acc[0][nt] = MFMA(al[0], bh[nt], acc[0][nt]);
    acc[1][nt] = MFMA(al[1], bh[nt], acc[1][nt]);
  }
}

__device__ __forceinline__ void computeH(const unsigned short* sbl, const Areg& a, float4v (&acc)[2][4]){
#pragma unroll
  for (int s = 0; s < 2; s++){
    short8 bh[4], bl[4];
    loadB(sbl + s * 4096, bh, bl);
    mfma3(a.h[s], a.l[s], bh, bl, acc);
  }
}

__device__ __forceinline__ void computeX(const float4v (&xf)[2][2][2], const unsigned short* sbl,
                                         float4v (&acc)[2][4]){
#pragma unroll
  for (int s = 0; s < 2; s++){
    short8 ah[2], al[2];
#pragma unroll
    for (int m = 0; m < 2; m++){
      short8 hi8, lo8;
#pragma unroll
      for (int j = 0; j < 8; j++){
        float x = (j < 4) ? xf[s][m][0][j] : xf[s][m][1][j - 4];
        unsigned short hb = f2bf(x);
        hi8[j] = (short)hb;
        lo8[j] = (short)f2bf(x - bf2f(hb));
      }
      ah[m] = hi8; al[m] = lo8;
    }
    short8 bh[4], bl[4];
    loadB(sbl + s * 4096, bh, bl);
    mfma3(ah, al, bh, bl, acc);
  }
}

__global__ void __launch_bounds__(512, 2) lstm_coop(
    const float* __restrict__ hist, const float* __restrict__ blstm,
    const unsigned short* __restrict__ wp,
    unsigned short* __restrict__ hp_hi, unsigned short* __restrict__ hp_lo,
    float* __restrict__ cfin, unsigned* __restrict__ flags){
  __shared__ __align__(16) unsigned short stage[2 * SBUF];  // 64 KiB double buffer
  __shared__ __align__(16) float red[8192];                 // 32 KiB K-partial exchange

  int b = blockIdx.x;
  int xcd = b & 7, jj = b >> 3;
  int nb = xcd * 8 + (jj & 7);          // XCD-local nb for L2 locality
  int mb = jj >> 3;                     // == b >> 6 ; barrier group
  int tid = threadIdx.x;
  int w = tid >> 6, lane = tid & 63;
  int kg = w >> 2, wr = w & 3;
  int u = lane & 15, q = lane >> 4;
  int rbase = mb * 128 + wr * 32;

  const unsigned short* wp_nb = wp + (size_t)nb * WP_NB;

  float bias_v[4];
#pragma unroll
  for (int nt = 0; nt < 4; nt++) bias_v[nt] = blstm[nt * H_ + nb * 16 + u];

  int rowA0 = rbase + u;                       // A-fragment rows (m=0 tile)
  int aoff0 = rowA0 * 32 + q * 8;              // elems; + hseg*16384 (+512 for m=1)
  const float* xb0 = hist + (size_t)rowA0 * (T_ * F_) + q * 8;

  // h write offsets (C/D layout: unit = lane&15, row = q*4 + r (+16m)); this wave stores m = kg
  int hsegw = nb >> 1;
  int kin = (nb & 1) * 16 + u;
  int howm = hsegw * 16384 + (rbase + 16 * kg + q * 4) * 32 + kin;
  int rowc = rbase + 16 * kg + q * 4;

  float cst[4];                                // c-state for this wave's m = kg rows
#pragma unroll
  for (int r = 0; r < 4; r++) cst[r] = 0.f;

  int c0k = 4 + kg * 16;

  // prologue: stage phase 0 of t=0, prefetch x(t=0)
  stage_phase(wp_nb, stage, 0, w, lane);
  Areg A0, A1;
  float4v xf[2][2][2];
  issueXF(xb0, 0, kg, xf);
  int cb = 0;

#pragma unroll 1
  for (int t = 0; t < T_; ++t){
    int bufr = t & 1, bufw = bufr ^ 1;
    const unsigned short* rh = hp_hi + bufr * HPBUF;
    const unsigned short* rl = hp_lo + bufr * HPBUF;

    float4v acc[2][4];
#pragma unroll
    for (int m = 0; m < 2; m++)
#pragma unroll
      for (int nt = 0; nt < 4; nt++) acc[m][nt] = (float4v){0.f, 0.f, 0.f, 0.f};

    // ---- phase 0: x columns (no h dependency); wave0 polls group barrier meanwhile ----
    __syncthreads();                                         // stage(0)+xf drained
    stage_phase(wp_nb, stage + (cb ^ 1) * SBUF, 1, w, lane);
    if (t && w == 0){
      const unsigned* f = flags + t * NBLK + (mb << 6);      // own 64-block group
      int ok;
      do {
        ok = (__hip_atomic_load(&f[lane], __ATOMIC_RELAXED, __HIP_MEMORY_SCOPE_AGENT) != 0u);
        if (__all(ok)) break;
        __builtin_amdgcn_s_sleep(2);
      } while (1);
      // no acquire fence: h is read via system-scope loads from the point of coherence,
      // so L2 is never invalidated and W/x stay L2-resident across all 256 steps.
    }
    computeX(xf, stage + cb * SBUF + kg * 8192 + lane * 8, acc);
    if (t) __syncthreads();                                  // order all waves after the poll
    issueA(rh, rl, aoff0, c0k, A0);                          // prefetch A(1)
    cb ^= 1;

    // ---- phases 1..8: h columns, A prefetched one phase ahead ----
#pragma unroll
    for (int pq = 0; pq < 4; pq++){
      const int p1 = 1 + 2 * pq, p2 = 2 + 2 * pq;
      __syncthreads();                                       // stage(p1)+A(p1) drained
      stage_phase(wp_nb, stage + (cb ^ 1) * SBUF, p1 + 1, w, lane);
      issueA(rh, rl, aoff0, c0k + p1 * 2, A1);               // A(p1+1)
      computeH(stage + cb * SBUF + kg * 8192 + lane * 8, A0, acc);
      cb ^= 1;
      __syncthreads();                                       // stage(p2)+A(p2) drained
      stage_phase(wp_nb, stage + (cb ^ 1) * SBUF, (p2 < 8) ? p2 + 1 : 0, w, lane);
      if (p2 < 8) issueA(rh, rl, aoff0, c0k + p2 * 2, A0);   // A(p2+1)
      else        issueXF(xb0, (t + 1 < T_) ? t + 1 : t, kg, xf);  // x(t+1)
      computeH(stage + cb * SBUF + kg * 8192 + lane * 8, A1, acc);
      cb ^= 1;
    }

    // ---- cross-K exchange: each kg finalizes its own m (= kg) tile ----
    __syncthreads();                           // all compute done; red region free
    if (kg == 0){                              // hand m=1 partial to kg1
#pragma unroll
      for (int nt = 0; nt < 4; nt++)
        *(float4v*)&red[4096 + ((wr * 4 + nt) * 64 + lane) * 4] = acc[1][nt];
    } else {                                   // hand m=0 partial to kg0
#pragma unroll
      for (int nt = 0; nt < 4; nt++)
        *(float4v*)&red[((wr * 4 + nt) * 64 + lane) * 4] = acc[0][nt];
    }
    __syncthreads();

    unsigned short* wh = hp_hi + bufw * HPBUF;
    unsigned short* wl2 = hp_lo + bufw * HPBUF;
    {
      float4v am[4];
      if (kg == 0){
#pragma unroll
        for (int nt = 0; nt < 4; nt++)
          am[nt] = acc[0][nt] + *(const float4v*)&red[((wr * 4 + nt) * 64 + lane) * 4];
      } else {
#pragma unroll
        for (int nt = 0; nt < 4; nt++)
          am[nt] = acc[1][nt] + *(const float4v*)&red[4096 + ((wr * 4 + nt) * 64 + lane) * 4];
      }
#pragma unroll
      for (int r = 0; r < 4; r++){
        float zi = am[0][r] + bias_v[0];
        float zj = am[1][r] + bias_v[1];
        float zf = am[2][r] + bias_v[2];
        float zo = am[3][r] + bias_v[3];
        float co = cst[r];
        float cn = sigf(zf + 1.f) * co + sigf(zi) * tanh_f(zj);
        float hn = sigf(zo) * tanh_f(cn);
        cst[r] = cn;
        int off = howm + r * 32;
        unsigned short hb = f2bf(hn);
        st2_sys(&wh[off], hb);                               // write-through to coherence point
        st2_sys(&wl2[off], f2bf(hn - bf2f(hb)));
        if (t == T_ - 1)
          cfin[(size_t)(rowc + r) * H_ + nb * 16 + u] = cn;
      }
    }
    __syncthreads();                           // drains vmcnt: h stores acked at coherence point
    if (tid == 0 && t + 1 < T_){
      __hip_atomic_store(&flags[(t + 1) * NBLK + b], 1u, __ATOMIC_RELEASE,
                         __HIP_MEMORY_SCOPE_AGENT);          // release-arrive for step t+1
    }
  }
}

// ---------------- head ----------------
__global__ void __launch_bounds__(256) build_feat(const float* __restrict__ head,
    const float* __restrict__ cfin, const unsigned short* __restrict__ hh,
    const unsigned short* __restrict__ hl, float* __restrict__ feat){
  int row = blockIdx.x;
  for (int kp = threadIdx.x; kp < 2080; kp += 256){
    float v;
    if (kp < 2) v = head[row * 3 + 1 + kp];
    else if (kp < 1026) v = cfin[(size_t)row * H_ + (kp - 2)];
    else if (kp < 2050){
      int n = kp - 1026;
      int off = (n >> 5) * 16384 + row * 32 + ((n & 31) >> 3) * 8 + (n & 7);
      v = bf2f(hh[off]) + bf2f(hl[off]);
    } else v = 0.f;
    feat[(size_t)row * 2080 + kp] = v;
  }
}

__global__ void __launch_bounds__(256) mlp_head(const float* __restrict__ feat,
    const float* __restrict__ W3, const float* __restrict__ b3,
    const float* __restrict__ W4, const float* __restrict__ b4,
    const float* __restrict__ W5, const float* __restrict__ b5,
    const float* __restrict__ W6, const float* __restrict__ b6,
    float* __restrict__ G){
  __shared__ float ftile[64][33];
  int bid = blockIdx.x;
  int mb = bid >> 5, nbk = bid & 31;
  int tid = threadIdx.x;
  int tr = tid >> 4, tc = tid & 15;
  int mat = nbk >> 3;
  const float* Wm = (mat == 0) ? W3 : (mat == 1) ? W4 : (mat == 2) ? W5 : W6;
  const float* bm = (mat == 0) ? b3 : (mat == 1) ? b4 : (mat == 2) ? b5 : b6;
  int lc = (nbk & 7) * 64 + tc * 4;
  int r0 = mb * 64;
  float racc[4][4] = {};
  for (int k0 = 0; k0 < 2080; k0 += 32){
    int rr = tid >> 3, cc = (tid & 7) * 4;
    float4v v0 = *(const float4v*)&feat[(size_t)(r0 + rr) * 2080 + k0 + cc];
    float4v v1 = *(const float4v*)&feat[(size_t)(r0 + rr + 32) * 2080 + k0 + cc];
#pragma unroll
    for (int i = 0; i < 4; i++){ ftile[rr][cc + i] = v0[i]; ftile[rr + 32][cc + i] = v1[i]; }
    __syncthreads();
#pragma unroll 4
    for (int kk = 0; kk < 32; kk++){
      int k = k0 + kk;
      float4v bv = (float4v){0.f, 0.f, 0.f, 0.f};
      if (k < 2050) bv = *(const float4v*)&Wm[(size_t)k * 512 + lc];
      float a0 = ftile[tr * 4 + 0][kk];
      float a1 = ftile[tr * 4 + 1][kk];
      float a2 = ftile[tr * 4 + 2][kk];
      float a3 = ftile[tr * 4 + 3][kk];
#pragma unroll
      for (int j = 0; j < 4; j++){
        racc[0][j] += a0 * bv[j]; racc[1][j] += a1 * bv[j];
        racc[2][j] += a2 * bv[j]; racc[3][j] += a3 * bv[j];
      }
    }
    __syncthreads();
  }
#pragma unroll
  for (int i = 0; i < 4; i++){
    float4v v;
#pragma unroll
    for (int j = 0; j < 4; j++){
      float x = racc[i][j] + bm[lc + j];
      v[j] = fmaxf(x, 0.f);
    }
    *(float4v*)&G[(size_t)(r0 + tr * 4 + i) * 2048 + nbk * 64 + tc * 4] = v;
  }
}

__global__ void __launch_bounds__(256) final_q(const float* __restrict__ G,
    const float* __restrict__ head, const float* __restrict__ tq, const int* __restrict__ act,
    const float* __restrict__ Wsv, const float* __restrict__ bsv,
    const float* __restrict__ Wbv, const float* __restrict__ bbv,
    const float* __restrict__ Wsh, const float* __restrict__ bsh,
    const float* __restrict__ Wbh, const float* __restrict__ bbh,
    float* __restrict__ out){
  int row = blockIdx.x, tid = threadIdx.x;
  const float* g = G + (size_t)row * 2048;
  float s0=0,s1=0,s2=0,s3=0,s4=0,s5=0;
  for (int k = tid; k < 512; k += 256){
    float vlp = g[k], qlp = g[512 + k], vle = g[1024 + k], qle = g[1536 + k];
    s0 += vlp * Wsv[k];
    s1 += qlp * Wsh[2 * k];  s2 += qlp * Wsh[2 * k + 1];
    s3 += vle * Wbv[k];
    s4 += qle * Wbh[2 * k];  s5 += qle * Wbh[2 * k + 1];
  }
#pragma unroll
  for (int off = 32; off; off >>= 1){
    s0 += __shfl_down(s0, off); s1 += __shfl_down(s1, off); s2 += __shfl_down(s2, off);
    s3 += __shfl_down(s3, off); s4 += __shfl_down(s4, off); s5 += __shfl_down(s5, off);
  }
  __shared__ float red[4][6];
  int w = tid >> 6, lane = tid & 63;
  if (lane == 0){ red[w][0]=s0; red[w][1]=s1; red[w][2]=s2; red[w][3]=s3; red[w][4]=s4; red[w][5]=s5; }
  __syncthreads();
  if (tid == 0){
    float r[6];
#pragma unroll
    for (int i = 0; i < 6; i++) r[i] = red[0][i] + red[1][i] + red[2][i] + red[3][i];
    float pa0 = r[1] + bsh[0], pa1 = r[2] + bsh[1];
    float pv  = r[0] + bsv[0];
    float pm  = 0.5f * (pa0 + pa1);
    float pQ0 = pa0 - pm + pv, pQ1 = pa1 - pm + pv;
    float ea0 = r[4] + bbh[0], ea1 = r[5] + bbh[1];
    float ev  = r[3] + bbv[0];
    float em  = 0.5f * (ea0 + ea1);
    float eQ0 = ea0 - em + ev, eQ1 = ea1 - em + ev;
    bool isp = (head[row * 3] != 0.f);
    float Q0 = isp ? pQ0 : eQ0;
    float Q1 = isp ? eQ1 : pQ1;   // mask col1 = (1-is_pos)!=0
    float gr = (Q1 > Q0) ? 1.f : 0.f;
    int a = act[row];
    float iv = (a == 0) ? Q0 : Q1;
    float d = tq[row] - iv;
    atomicAdd(out, d * d * (1.f / 512.f));
    out[1 + 2 * row] = Q0;
    out[2 + 2 * row] = Q1;
    out[1025 + row] = gr;
  }
}

// ---------------- launch ----------------
extern "C" void kernel_launch(void* const* d_in, const int* in_sizes, int n_in,
                              void* d_out, int out_size, void* d_ws, size_t ws_size,
                              hipStream_t stream){
  const float* hist = (const float*)d_in[0];
  const float* head = (const float*)d_in[1];
  const float* tq   = (const float*)d_in[2];
  const int*   act  = (const int*)d_in[3];
  const float* Wl   = (const float*)d_in[4];
  const float* bl   = (const float*)d_in[5];
  const float* W3 = (const float*)d_in[6];  const float* b3 = (const float*)d_in[7];
  const float* W4 = (const float*)d_in[8];  const float* b4 = (const float*)d_in[9];
  const float* W5 = (const float*)d_in[10]; const float* b5 = (const float*)d_in[11];
  const float* W6 = (const float*)d_in[12]; const float* b6 = (const float*)d_in[13];
  const float* Wsv = (const float*)d_in[14]; const float* bsv = (const float*)d_in[15];
  const float* Wbv = (const float*)d_in[16]; const float* bbv = (const float*)d_in[17];
  const float* Wsh = (const float*)d_in[18]; const float* bsh = (const float*)d_in[19];
  const float* Wbh = (const float*)d_in[20]; const float* bbh = (const float*)d_in[21];
  float* out = (float*)d_out;

  char* ws = (char*)d_ws;
  unsigned* flags      = (unsigned*)ws;                       // 256*256*4 = 262144
  unsigned short* hp_hi = (unsigned short*)(ws + 262144);      // 2 MiB
  unsigned short* hp_lo = (unsigned short*)(ws + 2359296);     // 2 MiB
  unsigned short* wp    = (unsigned short*)(ws + 4456448);     // 18.87 MB
  float* cfin = (float*)(ws + 23330816);                       // 2 MiB
  float* feat = (float*)(ws + 25427968);                       // 4.26 MB
  float* G    = (float*)(ws + 29687808);                       // 4.19 MB -> total ~33.9 MB

  // zero barrier flags + both h double-buffers (h(-1) = 0)
  hipMemsetAsync(ws, 0, 4456448, stream);
  hipMemsetAsync(d_out, 0, sizeof(float), stream);             // loss accumulator

  pack_w<<<dim3(64 * 36), dim3(256), 0, stream>>>(Wl, wp);

  void* args[] = {(void*)&hist, (void*)&bl, (void*)&wp, (void*)&hp_hi,
                  (void*)&hp_lo, (void*)&cfin, (void*)&flags};
  hipLaunchCooperativeKernel((void*)lstm_coop, dim3(NBLK), dim3(512), args, 0, stream);

  build_feat<<<dim3(512), dim3(256), 0, stream>>>(head, cfin, hp_hi, hp_lo, feat);
  mlp_head<<<dim3(256), dim3(256), 0, stream>>>(feat, W3, b3, W4, b4, W5, b5, W6, b6, G);
  final_q<<<dim3(512), dim3(256), 0, stream>>>(G, head, tq, act,
      Wsv, bsv, Wbv, bbv, Wsh, bsh, Wbh, bbh, out);
}

// Round 7
// 6636.242 us; speedup vs baseline: 1.2646x; 1.1621x over previous
//
#include <hip/hip_runtime.h>
#include <hip/hip_bf16.h>

#define B_ 512
#define T_ 256
#define F_ 128
#define H_ 1024
#define KD 1152          // F_ + H_
#define NBLK 256
#define HPBUF 524288     // elems per hpack buffer: 32 hseg * 512 rows * 32
#define WP_NB 147456     // elems per nb slice of packed W: 36 c32 * 8 frags * 512
#define WLDS_BYTES 147456  // dynamic LDS: W-hi resident, 36 c32 * 4 frags * 1 KiB

typedef __attribute__((ext_vector_type(8))) short short8;
typedef __attribute__((ext_vector_type(4))) float float4v;

#define MFMA(a,b,c) __builtin_amdgcn_mfma_f32_16x16x32_bf16(a,b,c,0,0,0)

__device__ __forceinline__ unsigned short f2bf(float x){
  unsigned u = __float_as_uint(x);
  unsigned r = (u + 0x7fffu + ((u >> 16) & 1u)) >> 16;
  return (unsigned short)r;
}
__device__ __forceinline__ float bf2f(unsigned short b){
  return __uint_as_float(((unsigned)b) << 16);
}
__device__ __forceinline__ float sigf(float x){ return 1.f / (1.f + __expf(-x)); }
__device__ __forceinline__ float tanh_f(float x){
  float e = __expf(2.f * x);
  return (e - 1.f) / (e + 1.f);
}

// async global->LDS copy, 16B per lane. lbase must be wave-uniform; HW adds lane*16.
__device__ __forceinline__ void cp16(const unsigned short* g, unsigned short* lbase, int lane){
#if defined(__has_builtin) && __has_builtin(__builtin_amdgcn_global_load_lds)
  __builtin_amdgcn_global_load_lds((const __attribute__((address_space(1))) unsigned int*)g,
                                   (__attribute__((address_space(3))) unsigned int*)lbase, 16, 0, 0);
#else
  *(short8*)(lbase + lane * 8) = *(const short8*)g;
#endif
}

// ---------------- W pre-pack: split hi/lo bf16 and lay out in MFMA B-fragment order -------------
// wp[nb][c32][frag 0..7][lane*8+j], frag 0..3 = hi for ntile(gate) 0..3, 4..7 = lo.
// (lo frags unused by the W-resident kernel; pack cost is one-time.)
__global__ void __launch_bounds__(256) pack_w(const float* __restrict__ Wl, unsigned short* __restrict__ wp){
  int bid = blockIdx.x;                 // 64*36
  int nb = bid / 36, c32 = bid % 36;
  int tid = threadIdx.x;
  int nt = tid >> 6, lane = tid & 63;
  int u = lane & 15, q = lane >> 4;
  int gcol = nt * H_ + nb * 16 + u;     // ntile == gate
  int k0 = c32 * 32 + q * 8;
  short8 hi, lo;
#pragma unroll
  for (int j = 0; j < 8; j++){
    float x = Wl[(size_t)(k0 + j) * 4096 + gcol];
    unsigned short hb = f2bf(x);
    hi[j] = (short)hb;
    lo[j] = (short)f2bf(x - bf2f(hb));
  }
  size_t base = (size_t)(nb * 36 + c32) * 8;
  *(short8*)&wp[(base + nt) * 512 + lane * 8] = hi;
  *(short8*)&wp[(base + 4 + nt) * 512 + lane * 8] = lo;
}

// ---------------- persistent cooperative LSTM kernel (W-resident in dynamic LDS) ----------------
// 256 blocks (1/CU), 256 threads (4 waves). Block = (nb, mb): nb 0..63 (16 N-cols),
// mb 0..3 (128 rows). Wave w owns rows rbase..rbase+31 (2 m-tiles), FULL K.
// W-hi (144 KiB) loaded to LDS once; no staging, no cross-wave reduction.
struct Areg { short8 h[2]; short8 l[2]; };   // [m]

__device__ __forceinline__ void issueA(const unsigned short* __restrict__ rh,
                                       const unsigned short* __restrict__ rl,
                                       int aoff0, int c32, Areg& d){
  int off = (c32 - 4) * 16384 + aoff0;
  d.h[0] = *(const short8*)(rh + off);
  d.h[1] = *(const short8*)(rh + off + 512);
  d.l[0] = *(const short8*)(rl + off);
  d.l[1] = *(const short8*)(rl + off + 512);
}

__device__ __forceinline__ void issueXF4(const float* __restrict__ xb0, int tn,
                                         float4v (&xf)[4][2][2]){
#pragma unroll
  for (int s = 0; s < 4; s++)
#pragma unroll
    for (int m = 0; m < 2; m++){
      const float* px = xb0 + (size_t)m * 16 * (T_ * F_) + tn * F_ + s * 32;
      xf[s][m][0] = *(const float4v*)px;
      xf[s][m][1] = *(const float4v*)(px + 4);
    }
}

// fb = &wlds[c32*2048 + lane*8]; 4 B-frag reads + 16 MFMA (A hi+lo x B hi)
__device__ __forceinline__ void computeH(const unsigned short* fb, const Areg& a,
                                         float4v (&acc)[2][4]){
  short8 bh[4];
#pragma unroll
  for (int nt = 0; nt < 4; nt++) bh[nt] = *(const short8*)(fb + nt * 512);
#pragma unroll
  for (int nt = 0; nt < 4; nt++){
    acc[0][nt] = MFMA(a.h[0], bh[nt], acc[0][nt]);
    acc[1][nt] = MFMA(a.h[1], bh[nt], acc[1][nt]);
  }
#pragma unroll
  for (int nt = 0; nt < 4; nt++){
    acc[0][nt] = MFMA(a.l[0], bh[nt], acc[0][nt]);
    acc[1][nt] = MFMA(a.l[1], bh[nt], acc[1][nt]);
  }
}

__device__ __forceinline__ void computeX4(const float4v (&xf)[4][2][2],
                                          const unsigned short* wl0,
                                          float4v (&acc)[2][4]){
#pragma unroll
  for (int s = 0; s < 4; s++){
    short8 ah[2], al[2];
#pragma unroll
    for (int m = 0; m < 2; m++){
      short8 hi8, lo8;
#pragma unroll
      for (int j = 0; j < 8; j++){
        float x = (j < 4) ? xf[s][m][0][j] : xf[s][m][1][j - 4];
        unsigned short hb = f2bf(x);
        hi8[j] = (short)hb;
        lo8[j] = (short)f2bf(x - bf2f(hb));
      }
      ah[m] = hi8; al[m] = lo8;
    }
    short8 bh[4];
#pragma unroll
    for (int nt = 0; nt < 4; nt++) bh[nt] = *(const short8*)(wl0 + s * 2048 + nt * 512);
#pragma unroll
    for (int nt = 0; nt < 4; nt++){
      acc[0][nt] = MFMA(ah[0], bh[nt], acc[0][nt]);
      acc[1][nt] = MFMA(ah[1], bh[nt], acc[1][nt]);
    }
#pragma unroll
    for (int nt = 0; nt < 4; nt++){
      acc[0][nt] = MFMA(al[0], bh[nt], acc[0][nt]);
      acc[1][nt] = MFMA(al[1], bh[nt], acc[1][nt]);
    }
  }
}

__global__ void __launch_bounds__(256, 1) lstm_coop(
    const float* __restrict__ hist, const float* __restrict__ blstm,
    const unsigned short* __restrict__ wp,
    unsigned short* __restrict__ hp_hi, unsigned short* __restrict__ hp_lo,
    float* __restrict__ cfin, unsigned* __restrict__ flags){
  extern __shared__ __align__(16) unsigned short wlds[];   // 144 KiB W-hi, resident all steps

  int b = blockIdx.x;
  int xcd = b & 7, jj = b >> 3;
  int nb = xcd * 8 + (jj & 7);          // XCD-local nb for L2 locality
  int mb = jj >> 3;                     // 0..3 ; 128-row group = barrier group
  int tid = threadIdx.x;
  int w = tid >> 6, lane = tid & 63;
  int u = lane & 15, q = lane >> 4;
  int rbase = mb * 128 + w * 32;

  const unsigned short* wp_nb = wp + (size_t)nb * WP_NB;

  // ---- one-time: W-hi -> LDS (144 frags of 1 KiB; wave w takes i = w, w+4, ...) ----
  for (int i = w; i < 144; i += 4)
    cp16(wp_nb + (size_t)((i >> 2) * 8 + (i & 3)) * 512 + lane * 8, &wlds[i * 512], lane);

  float bias_v[4];
#pragma unroll
  for (int nt = 0; nt < 4; nt++) bias_v[nt] = blstm[nt * H_ + nb * 16 + u];

  int rowA0 = rbase + u;                       // A-fragment rows (m=0 tile)
  int aoff0 = rowA0 * 32 + q * 8;              // elems; + hseg*16384 (+512 for m=1)
  const float* xb0 = hist + (size_t)rowA0 * (T_ * F_) + q * 8;

  // h write offsets (C/D layout: unit = lane&15, row = q*4 + r (+16m))
  int hsegw = nb >> 1;
  int kin = (nb & 1) * 16 + u;
  int howbase = hsegw * 16384 + (rbase + q * 4) * 32 + kin;

  float cst[2][4];
#pragma unroll
  for (int m = 0; m < 2; m++)
#pragma unroll
    for (int r = 0; r < 4; r++) cst[m][r] = 0.f;

  float4v xf[4][2][2];
  issueXF4(xb0, 0, xf);
  __syncthreads();                             // W-hi staged (barrier drains vmcnt)

#pragma unroll 1
  for (int t = 0; t < T_; ++t){
    int bufr = t & 1, bufw = bufr ^ 1;
    const unsigned short* rh = hp_hi + bufr * HPBUF;
    const unsigned short* rl = hp_lo + bufr * HPBUF;

    float4v acc[2][4];
#pragma unroll
    for (int m = 0; m < 2; m++)
#pragma unroll
      for (int nt = 0; nt < 4; nt++) acc[m][nt] = (float4v){0.f, 0.f, 0.f, 0.f};

    // ---- x-part (no h dependency); wave0 polls the group barrier meanwhile ----
    computeX4(xf, wlds + lane * 8, acc);
    if (t && w == 0){
      const unsigned* f = flags + t * NBLK + (mb << 6);    // own 64-block group
      int ok;
      do {
        ok = (__hip_atomic_load(&f[lane], __ATOMIC_RELAXED, __HIP_MEMORY_SCOPE_AGENT) != 0u);
        if (__all(ok)) break;
        __builtin_amdgcn_s_sleep(2);
      } while (1);
      __builtin_amdgcn_fence(__ATOMIC_ACQUIRE, "agent");   // L2 inv before any h(t-1) read
    }
    __syncthreads();                                       // all waves ordered after fence

    // ---- h loop: full K per wave, A register-prefetched 2 c32 ahead ----
    Areg A0, A1;
    issueA(rh, rl, aoff0, 4, A0);
    issueA(rh, rl, aoff0, 5, A1);
#pragma unroll 1
    for (int c = 4; c < 36; c += 2){
      computeH(&wlds[c * 2048 + lane * 8], A0, acc);
      if (c + 2 < 36) issueA(rh, rl, aoff0, c + 2, A0);
      else            issueXF4(xb0, (t + 1 < T_) ? t + 1 : t, xf);  // x(t+1)
      computeH(&wlds[(c + 1) * 2048 + lane * 8], A1, acc);
      if (c + 3 < 36) issueA(rh, rl, aoff0, c + 3, A1);
    }

    // ---- gate update (fully wave-local: this wave owns all 4 gates of its 32 rows) ----
    unsigned short* wh = hp_hi + bufw * HPBUF;
    unsigned short* wl2 = hp_lo + bufw * HPBUF;
#pragma unroll
    for (int m = 0; m < 2; m++){
#pragma unroll
      for (int r = 0; r < 4; r++){
        float zi = acc[m][0][r] + bias_v[0];
        float zj = acc[m][1][r] + bias_v[1];
        float zf = acc[m][2][r] + bias_v[2];
        float zo = acc[m][3][r] + bias_v[3];
        float co = cst[m][r];
        float cn = sigf(zf + 1.f) * co + sigf(zi) * tanh_f(zj);
        float hn = sigf(zo) * tanh_f(cn);
        cst[m][r] = cn;
        int off = howbase + (16 * m + r) * 32;
        unsigned short hb = f2bf(hn);
        wh[off] = hb;
        wl2[off] = f2bf(hn - bf2f(hb));
        if (t == T_ - 1){
          int row = rbase + 16 * m + q * 4 + r;
          cfin[(size_t)row * H_ + nb * 16 + u] = cn;
        }
      }
    }
    __syncthreads();                           // drains vmcnt: h stores complete at L2
    if (tid == 0 && t + 1 < T_){
      __builtin_amdgcn_fence(__ATOMIC_RELEASE, "agent");   // push h to coherence point
      __hip_atomic_store(&flags[(t + 1) * NBLK + b], 1u, __ATOMIC_RELAXED,
                         __HIP_MEMORY_SCOPE_AGENT);        // arrive for step t+1
    }
  }
}

// ---------------- head ----------------
__global__ void __launch_bounds__(256) build_feat(const float* __restrict__ head,
    const float* __restrict__ cfin, const unsigned short* __restrict__ hh,
    const unsigned short* __restrict__ hl, float* __restrict__ feat){
  int row = blockIdx.x;
  for (int kp = threadIdx.x; kp < 2080; kp += 256){
    float v;
    if (kp < 2) v = head[row * 3 + 1 + kp];
    else if (kp < 1026) v = cfin[(size_t)row * H_ + (kp - 2)];
    else if (kp < 2050){
      int n = kp - 1026;
      int off = (n >> 5) * 16384 + row * 32 + ((n & 31) >> 3) * 8 + (n & 7);
      v = bf2f(hh[off]) + bf2f(hl[off]);
    } else v = 0.f;
    feat[(size_t)row * 2080 + kp] = v;
  }
}

__global__ void __launch_bounds__(256) mlp_head(const float* __restrict__ feat,
    const float* __restrict__ W3, const float* __restrict__ b3,
    const float* __restrict__ W4, const float* __restrict__ b4,
    const float* __restrict__ W5, const float* __restrict__ b5,
    const float* __restrict__ W6, const float* __restrict__ b6,
    float* __restrict__ G){
  __shared__ float ftile[64][33];
  int bid = blockIdx.x;
  int mb = bid >> 5, nbk = bid & 31;
  int tid = threadIdx.x;
  int tr = tid >> 4, tc = tid & 15;
  int mat = nbk >> 3;
  const float* Wm = (mat == 0) ? W3 : (mat == 1) ? W4 : (mat == 2) ? W5 : W6;
  const float* bm = (mat == 0) ? b3 : (mat == 1) ? b4 : (mat == 2) ? b5 : b6;
  int lc = (nbk & 7) * 64 + tc * 4;
  int r0 = mb * 64;
  float racc[4][4] = {};
  for (int k0 = 0; k0 < 2080; k0 += 32){
    int rr = tid >> 3, cc = (tid & 7) * 4;
    float4v v0 = *(const float4v*)&feat[(size_t)(r0 + rr) * 2080 + k0 + cc];
    float4v v1 = *(const float4v*)&feat[(size_t)(r0 + rr + 32) * 2080 + k0 + cc];
#pragma unroll
    for (int i = 0; i < 4; i++){ ftile[rr][cc + i] = v0[i]; ftile[rr + 32][cc + i] = v1[i]; }
    __syncthreads();
#pragma unroll 4
    for (int kk = 0; kk < 32; kk++){
      int k = k0 + kk;
      float4v bv = (float4v){0.f, 0.f, 0.f, 0.f};
      if (k < 2050) bv = *(const float4v*)&Wm[(size_t)k * 512 + lc];
      float a0 = ftile[tr * 4 + 0][kk];
      float a1 = ftile[tr * 4 + 1][kk];
      float a2 = ftile[tr * 4 + 2][kk];
      float a3 = ftile[tr * 4 + 3][kk];
#pragma unroll
      for (int j = 0; j < 4; j++){
        racc[0][j] += a0 * bv[j]; racc[1][j] += a1 * bv[j];
        racc[2][j] += a2 * bv[j]; racc[3][j] += a3 * bv[j];
      }
    }
    __syncthreads();
  }
#pragma unroll
  for (int i = 0; i < 4; i++){
    float4v v;
#pragma unroll
    for (int j = 0; j < 4; j++){
      float x = racc[i][j] + bm[lc + j];
      v[j] = fmaxf(x, 0.f);
    }
    *(float4v*)&G[(size_t)(r0 + tr * 4 + i) * 2048 + nbk * 64 + tc * 4] = v;
  }
}

__global__ void __launch_bounds__(256) final_q(const float* __restrict__ G,
    const float* __restrict__ head, const float* __restrict__ tq, const int* __restrict__ act,
    const float* __restrict__ Wsv, const float* __restrict__ bsv,
    const float* __restrict__ Wbv, const float* __restrict__ bbv,
    const float* __restrict__ Wsh, const float* __restrict__ bsh,
    const float* __restrict__ Wbh, const float* __restrict__ bbh,
    float* __restrict__ out){
  int row = blockIdx.x, tid = threadIdx.x;
  const float* g = G + (size_t)row * 2048;
  float s0=0,s1=0,s2=0,s3=0,s4=0,s5=0;
  for (int k = tid; k < 512; k += 256){
    float vlp = g[k], qlp = g[512 + k], vle = g[1024 + k], qle = g[1536 + k];
    s0 += vlp * Wsv[k];
    s1 += qlp * Wsh[2 * k];  s2 += qlp * Wsh[2 * k + 1];
    s3 += vle * Wbv[k];
    s4 += qle * Wbh[2 * k];  s5 += qle * Wbh[2 * k + 1];
  }
#pragma unroll
  for (int off = 32; off; off >>= 1){
    s0 += __shfl_down(s0, off); s1 += __shfl_down(s1, off); s2 += __shfl_down(s2, off);
    s3 += __shfl_down(s3, off); s4 += __shfl_down(s4, off); s5 += __shfl_down(s5, off);
  }
  __shared__ float red[4][6];
  int w = tid >> 6, lane = tid & 63;
  if (lane == 0){ red[w][0]=s0; red[w][1]=s1; red[w][2]=s2; red[w][3]=s3; red[w][4]=s4; red[w][5]=s5; }
  __syncthreads();
  if (tid == 0){
    float r[6];
#pragma unroll
    for (int i = 0; i < 6; i++) r[i] = red[0][i] + red[1][i] + red[2][i] + red[3][i];
    float pa0 = r[1] + bsh[0], pa1 = r[2] + bsh[1];
    float pv  = r[0] + bsv[0];
    float pm  = 0.5f * (pa0 + pa1);
    float pQ0 = pa0 - pm + pv, pQ1 = pa1 - pm + pv;
    float ea0 = r[4] + bbh[0], ea1 = r[5] + bbh[1];
    float ev  = r[3] + bbv[0];
    float em  = 0.5f * (ea0 + ea1);
    float eQ0 = ea0 - em + ev, eQ1 = ea1 - em + ev;
    bool isp = (head[row * 3] != 0.f);
    float Q0 = isp ? pQ0 : eQ0;
    float Q1 = isp ? eQ1 : pQ1;   // mask col1 = (1-is_pos)!=0
    float gr = (Q1 > Q0) ? 1.f : 0.f;
    int a = act[row];
    float iv = (a == 0) ? Q0 : Q1;
    float d = tq[row] - iv;
    atomicAdd(out, d * d * (1.f / 512.f));
    out[1 + 2 * row] = Q0;
    out[2 + 2 * row] = Q1;
    out[1025 + row] = gr;
  }
}

// ---------------- launch ----------------
extern "C" void kernel_launch(void* const* d_in, const int* in_sizes, int n_in,
                              void* d_out, int out_size, void* d_ws, size_t ws_size,
                              hipStream_t stream){
  const float* hist = (const float*)d_in[0];
  const float* head = (const float*)d_in[1];
  const float* tq   = (const float*)d_in[2];
  const int*   act  = (const int*)d_in[3];
  const float* Wl   = (const float*)d_in[4];
  const float* bl   = (const float*)d_in[5];
  const float* W3 = (const float*)d_in[6];  const float* b3 = (const float*)d_in[7];
  const float* W4 = (const float*)d_in[8];  const float* b4 = (const float*)d_in[9];
  const float* W5 = (const float*)d_in[10]; const float* b5 = (const float*)d_in[11];
  const float* W6 = (const float*)d_in[12]; const float* b6 = (const float*)d_in[13];
  const float* Wsv = (const float*)d_in[14]; const float* bsv = (const float*)d_in[15];
  const float* Wbv = (const float*)d_in[16]; const float* bbv = (const float*)d_in[17];
  const float* Wsh = (const float*)d_in[18]; const float* bsh = (const float*)d_in[19];
  const float* Wbh = (const float*)d_in[20]; const float* bbh = (const float*)d_in[21];
  float* out = (float*)d_out;

  char* ws = (char*)d_ws;
  unsigned* flags      = (unsigned*)ws;                       // 256*256*4 = 262144
  unsigned short* hp_hi = (unsigned short*)(ws + 262144);      // 2 MiB
  unsigned short* hp_lo = (unsigned short*)(ws + 2359296);     // 2 MiB
  unsigned short* wp    = (unsigned short*)(ws + 4456448);     // 18.87 MB
  float* cfin = (float*)(ws + 23330816);                       // 2 MiB
  float* feat = (float*)(ws + 25427968);                       // 4.26 MB
  float* G    = (float*)(ws + 29687808);                       // 4.19 MB -> total ~33.9 MB

  // opt in to >default dynamic LDS (144 KiB) for the persistent kernel
  static int lds_attr_set = 0;
  if (!lds_attr_set){
    hipFuncSetAttribute(reinterpret_cast<const void*>(lstm_coop),
                        hipFuncAttributeMaxDynamicSharedMemorySize, WLDS_BYTES);
    lds_attr_set = 1;
  }

  // zero barrier flags + both h double-buffers (h(-1) = 0)
  hipMemsetAsync(ws, 0, 4456448, stream);
  hipMemsetAsync(d_out, 0, sizeof(float), stream);             // loss accumulator

  pack_w<<<dim3(64 * 36), dim3(256), 0, stream>>>(Wl, wp);

  void* args[] = {(void*)&hist, (void*)&bl, (void*)&wp, (void*)&hp_hi,
                  (void*)&hp_lo, (void*)&cfin, (void*)&flags};
  hipError_t ce = hipLaunchCooperativeKernel((void*)lstm_coop, dim3(NBLK), dim3(256),
                                             args, WLDS_BYTES, stream);
  if (ce != hipSuccess){
    // fallback: plain launch. Co-residency is structural: 144 KiB LDS forces 1 block/CU
    // and grid == 256 == #CUs, so all blocks are resident; flag protocol needs no coop API.
    lstm_coop<<<dim3(NBLK), dim3(256), WLDS_BYTES, stream>>>(hist, bl, wp, hp_hi,
                                                             hp_lo, cfin, flags);
  }

  build_feat<<<dim3(512), dim3(256), 0, stream>>>(head, cfin, hp_hi, hp_lo, feat);
  mlp_head<<<dim3(256), dim3(256), 0, stream>>>(feat, W3, b3, W4, b4, W5, b5, W6, b6, G);
  final_q<<<dim3(512), dim3(256), 0, stream>>>(G, head, tq, act,
      Wsv, bsv, Wbv, bbv, Wsh, bsh, Wbh, bbh, out);
}

// Round 8
// 6347.906 us; speedup vs baseline: 1.3220x; 1.0454x over previous
//
#include <hip/hip_runtime.h>
#include <hip/hip_bf16.h>

#define B_ 512
#define T_ 256
#define F_ 128
#define H_ 1024
#define KD 1152          // F_ + H_
#define NBLK 256
#define HPBUF 524288     // elems per hpack buffer: 32 hseg * 512 rows * 32
#define WP_NB 147456     // elems per nb slice of packed W: 36 c32 * 8 frags * 512
#define WLDS_BYTES 147456  // dynamic LDS: W-hi resident, 36 c32 * 4 frags * 1 KiB

typedef __attribute__((ext_vector_type(8))) short short8;
typedef __attribute__((ext_vector_type(4))) float float4v;

#define MFMA(a,b,c) __builtin_amdgcn_mfma_f32_16x16x32_bf16(a,b,c,0,0,0)

__device__ __forceinline__ unsigned short f2bf(float x){
  unsigned u = __float_as_uint(x);
  unsigned r = (u + 0x7fffu + ((u >> 16) & 1u)) >> 16;
  return (unsigned short)r;
}
__device__ __forceinline__ float bf2f(unsigned short b){
  return __uint_as_float(((unsigned)b) << 16);
}
__device__ __forceinline__ float sigf(float x){ return 1.f / (1.f + __expf(-x)); }
__device__ __forceinline__ float tanh_f(float x){
  float e = __expf(2.f * x);
  return (e - 1.f) / (e + 1.f);
}

// async global->LDS copy, 16B per lane. lbase must be wave-uniform; HW adds lane*16.
__device__ __forceinline__ void cp16(const unsigned short* g, unsigned short* lbase, int lane){
#if defined(__has_builtin) && __has_builtin(__builtin_amdgcn_global_load_lds)
  __builtin_amdgcn_global_load_lds((const __attribute__((address_space(1))) unsigned int*)g,
                                   (__attribute__((address_space(3))) unsigned int*)lbase, 16, 0, 0);
#else
  *(short8*)(lbase + lane * 8) = *(const short8*)g;
#endif
}

// ---------------- W pre-pack: split hi/lo bf16 and lay out in MFMA B-fragment order -------------
// wp[nb][c32][frag 0..7][lane*8+j], frag 0..3 = hi for ntile(gate) 0..3, 4..7 = lo.
// (lo frags unused by the W-resident kernel; pack cost is one-time.)
__global__ void __launch_bounds__(256) pack_w(const float* __restrict__ Wl, unsigned short* __restrict__ wp){
  int bid = blockIdx.x;                 // 64*36
  int nb = bid / 36, c32 = bid % 36;
  int tid = threadIdx.x;
  int nt = tid >> 6, lane = tid & 63;
  int u = lane & 15, q = lane >> 4;
  int gcol = nt * H_ + nb * 16 + u;     // ntile == gate
  int k0 = c32 * 32 + q * 8;
  short8 hi, lo;
#pragma unroll
  for (int j = 0; j < 8; j++){
    float x = Wl[(size_t)(k0 + j) * 4096 + gcol];
    unsigned short hb = f2bf(x);
    hi[j] = (short)hb;
    lo[j] = (short)f2bf(x - bf2f(hb));
  }
  size_t base = (size_t)(nb * 36 + c32) * 8;
  *(short8*)&wp[(base + nt) * 512 + lane * 8] = hi;
  *(short8*)&wp[(base + 4 + nt) * 512 + lane * 8] = lo;
}

// ---------------- persistent cooperative LSTM kernel (W-resident in dynamic LDS) ----------------
// 256 blocks (1/CU), 512 threads (8 waves, 2/SIMD). Block = (nb, mb): nb 0..63 (16 N-cols),
// mb 0..3 (128 rows). Wave w owns rows rbase = mb*128 + w*16 (ONE 16-row m-tile), FULL K.
// W-hi (144 KiB) in LDS once; no staging, no cross-wave reduction; gates lane-local.
struct Areg { short8 h; short8 l; };

__device__ __forceinline__ void issueA(const unsigned short* __restrict__ rh,
                                       const unsigned short* __restrict__ rl,
                                       int aoff0, int c32, Areg& d){
  int off = (c32 - 4) * 16384 + aoff0;
  d.h = *(const short8*)(rh + off);
  d.l = *(const short8*)(rl + off);
}

__device__ __forceinline__ void issueXF4(const float* __restrict__ xb0, int tn,
                                         float4v (&xf)[4][2]){
#pragma unroll
  for (int s = 0; s < 4; s++){
    const float* px = xb0 + tn * F_ + s * 32;
    xf[s][0] = *(const float4v*)px;
    xf[s][1] = *(const float4v*)(px + 4);
  }
}

// fb = &wlds[c32*2048 + lane*8]; 4 B-frag reads + 8 MFMA (A hi+lo x B hi)
__device__ __forceinline__ void computeH(const unsigned short* fb, const Areg& a,
                                         float4v (&acc)[4]){
  short8 bh[4];
#pragma unroll
  for (int nt = 0; nt < 4; nt++) bh[nt] = *(const short8*)(fb + nt * 512);
#pragma unroll
  for (int nt = 0; nt < 4; nt++) acc[nt] = MFMA(a.h, bh[nt], acc[nt]);
#pragma unroll
  for (int nt = 0; nt < 4; nt++) acc[nt] = MFMA(a.l, bh[nt], acc[nt]);
}

__device__ __forceinline__ void computeX4(const float4v (&xf)[4][2],
                                          const unsigned short* wl0,
                                          float4v (&acc)[4]){
#pragma unroll
  for (int s = 0; s < 4; s++){
    short8 hi8, lo8;
#pragma unroll
    for (int j = 0; j < 8; j++){
      float x = (j < 4) ? xf[s][0][j] : xf[s][1][j - 4];
      unsigned short hb = f2bf(x);
      hi8[j] = (short)hb;
      lo8[j] = (short)f2bf(x - bf2f(hb));
    }
    short8 bh[4];
#pragma unroll
    for (int nt = 0; nt < 4; nt++) bh[nt] = *(const short8*)(wl0 + s * 2048 + nt * 512);
#pragma unroll
    for (int nt = 0; nt < 4; nt++) acc[nt] = MFMA(hi8, bh[nt], acc[nt]);
#pragma unroll
    for (int nt = 0; nt < 4; nt++) acc[nt] = MFMA(lo8, bh[nt], acc[nt]);
  }
}

__global__ void __launch_bounds__(512, 2) lstm_coop(
    const float* __restrict__ hist, const float* __restrict__ blstm,
    const unsigned short* __restrict__ wp,
    unsigned short* __restrict__ hp_hi, unsigned short* __restrict__ hp_lo,
    float* __restrict__ cfin, unsigned* __restrict__ flags){
  extern __shared__ __align__(16) unsigned short wlds[];   // 144 KiB W-hi, resident all steps

  int b = blockIdx.x;
  int xcd = b & 7, jj = b >> 3;
  int nb = xcd * 8 + (jj & 7);          // XCD-local nb for L2 locality
  int mb = jj >> 3;                     // 0..3 ; 128-row group = barrier group
  int tid = threadIdx.x;
  int w = tid >> 6, lane = tid & 63;    // 8 waves, wave w owns rows rbase..rbase+15
  int u = lane & 15, q = lane >> 4;
  int rbase = mb * 128 + w * 16;

  const unsigned short* wp_nb = wp + (size_t)nb * WP_NB;

  // ---- one-time: W-hi -> LDS (144 frags of 1 KiB; wave w takes i = w, w+8, ...) ----
  for (int i = w; i < 144; i += 8)
    cp16(wp_nb + (size_t)((i >> 2) * 8 + (i & 3)) * 512 + lane * 8, &wlds[i * 512], lane);

  float bias_v[4];
#pragma unroll
  for (int nt = 0; nt < 4; nt++) bias_v[nt] = blstm[nt * H_ + nb * 16 + u];

  int rowA0 = rbase + u;                       // A-fragment rows (16-row tile)
  int aoff0 = rowA0 * 32 + q * 8;              // elems; + hseg*16384
  const float* xb0 = hist + (size_t)rowA0 * (T_ * F_) + q * 8;

  // h write offsets (C/D layout: unit = lane&15, row = q*4 + r)
  int hsegw = nb >> 1;
  int kin = (nb & 1) * 16 + u;
  int howbase = hsegw * 16384 + (rbase + q * 4) * 32 + kin;

  float cst[4];
#pragma unroll
  for (int r = 0; r < 4; r++) cst[r] = 0.f;

  float4v xf[4][2];
  issueXF4(xb0, 0, xf);
  __syncthreads();                             // W-hi staged (barrier drains vmcnt)

#pragma unroll 1
  for (int t = 0; t < T_; ++t){
    int bufr = t & 1, bufw = bufr ^ 1;
    const unsigned short* rh = hp_hi + bufr * HPBUF;
    const unsigned short* rl = hp_lo + bufr * HPBUF;

    float4v acc[4];
#pragma unroll
    for (int nt = 0; nt < 4; nt++) acc[nt] = (float4v){0.f, 0.f, 0.f, 0.f};

    // ---- x-part (no h dependency); wave0 polls the group barrier meanwhile ----
    computeX4(xf, wlds + lane * 8, acc);
    if (t && w == 0){
      const unsigned* f = flags + t * NBLK + (mb << 6);    // own 64-block group
      int ok;
      do {
        ok = (__hip_atomic_load(&f[lane], __ATOMIC_RELAXED, __HIP_MEMORY_SCOPE_AGENT) != 0u);
        if (__all(ok)) break;
        __builtin_amdgcn_s_sleep(2);
      } while (1);
      __builtin_amdgcn_fence(__ATOMIC_ACQUIRE, "agent");   // L2 inv before any h(t-1) read
    }
    __syncthreads();                                       // all waves ordered after fence

    // ---- h loop: full K per wave, A register-prefetched 4 c32 ahead ----
    Areg A0, A1, A2, A3;
    issueA(rh, rl, aoff0, 4, A0);
    issueA(rh, rl, aoff0, 5, A1);
    issueA(rh, rl, aoff0, 6, A2);
    issueA(rh, rl, aoff0, 7, A3);
#pragma unroll 1
    for (int c = 4; c < 36; c += 4){
      computeH(&wlds[(c + 0) * 2048 + lane * 8], A0, acc);
      if (c + 4 < 36) issueA(rh, rl, aoff0, c + 4, A0);
      computeH(&wlds[(c + 1) * 2048 + lane * 8], A1, acc);
      if (c + 5 < 36) issueA(rh, rl, aoff0, c + 5, A1);
      else            issueXF4(xb0, (t + 1 < T_) ? t + 1 : t, xf);  // x(t+1)
      computeH(&wlds[(c + 2) * 2048 + lane * 8], A2, acc);
      if (c + 6 < 36) issueA(rh, rl, aoff0, c + 6, A2);
      computeH(&wlds[(c + 3) * 2048 + lane * 8], A3, acc);
      if (c + 7 < 36) issueA(rh, rl, aoff0, c + 7, A3);
    }

    // ---- gate update (fully wave-local: this wave owns all 4 gates of its 16 rows) ----
    unsigned short* wh = hp_hi + bufw * HPBUF;
    unsigned short* wl2 = hp_lo + bufw * HPBUF;
#pragma unroll
    for (int r = 0; r < 4; r++){
      float zi = acc[0][r] + bias_v[0];
      float zj = acc[1][r] + bias_v[1];
      float zf = acc[2][r] + bias_v[2];
      float zo = acc[3][r] + bias_v[3];
      float co = cst[r];
      float cn = sigf(zf + 1.f) * co + sigf(zi) * tanh_f(zj);
      float hn = sigf(zo) * tanh_f(cn);
      cst[r] = cn;
      int off = howbase + r * 32;
      unsigned short hb = f2bf(hn);
      wh[off] = hb;
      wl2[off] = f2bf(hn - bf2f(hb));
      if (t == T_ - 1){
        int row = rbase + q * 4 + r;
        cfin[(size_t)row * H_ + nb * 16 + u] = cn;
      }
    }
    __syncthreads();                           // drains vmcnt: h stores complete at L2
    if (tid == 0 && t + 1 < T_){
      __builtin_amdgcn_fence(__ATOMIC_RELEASE, "agent");   // push h to coherence point
      __hip_atomic_store(&flags[(t + 1) * NBLK + b], 1u, __ATOMIC_RELAXED,
                         __HIP_MEMORY_SCOPE_AGENT);        // arrive for step t+1
    }
  }
}

// ---------------- head ----------------
__global__ void __launch_bounds__(256) build_feat(const float* __restrict__ head,
    const float* __restrict__ cfin, const unsigned short* __restrict__ hh,
    const unsigned short* __restrict__ hl, float* __restrict__ feat){
  int row = blockIdx.x;
  for (int kp = threadIdx.x; kp < 2080; kp += 256){
    float v;
    if (kp < 2) v = head[row * 3 + 1 + kp];
    else if (kp < 1026) v = cfin[(size_t)row * H_ + (kp - 2)];
    else if (kp < 2050){
      int n = kp - 1026;
      int off = (n >> 5) * 16384 + row * 32 + ((n & 31) >> 3) * 8 + (n & 7);
      v = bf2f(hh[off]) + bf2f(hl[off]);
    } else v = 0.f;
    feat[(size_t)row * 2080 + kp] = v;
  }
}

__global__ void __launch_bounds__(256) mlp_head(const float* __restrict__ feat,
    const float* __restrict__ W3, const float* __restrict__ b3,
    const float* __restrict__ W4, const float* __restrict__ b4,
    const float* __restrict__ W5, const float* __restrict__ b5,
    const float* __restrict__ W6, const float* __restrict__ b6,
    float* __restrict__ G){
  __shared__ float ftile[64][33];
  int bid = blockIdx.x;
  int mb = bid >> 5, nbk = bid & 31;
  int tid = threadIdx.x;
  int tr = tid >> 4, tc = tid & 15;
  int mat = nbk >> 3;
  const float* Wm = (mat == 0) ? W3 : (mat == 1) ? W4 : (mat == 2) ? W5 : W6;
  const float* bm = (mat == 0) ? b3 : (mat == 1) ? b4 : (mat == 2) ? b5 : b6;
  int lc = (nbk & 7) * 64 + tc * 4;
  int r0 = mb * 64;
  float racc[4][4] = {};
  for (int k0 = 0; k0 < 2080; k0 += 32){
    int rr = tid >> 3, cc = (tid & 7) * 4;
    float4v v0 = *(const float4v*)&feat[(size_t)(r0 + rr) * 2080 + k0 + cc];
    float4v v1 = *(const float4v*)&feat[(size_t)(r0 + rr + 32) * 2080 + k0 + cc];
#pragma unroll
    for (int i = 0; i < 4; i++){ ftile[rr][cc + i] = v0[i]; ftile[rr + 32][cc + i] = v1[i]; }
    __syncthreads();
#pragma unroll 4
    for (int kk = 0; kk < 32; kk++){
      int k = k0 + kk;
      float4v bv = (float4v){0.f, 0.f, 0.f, 0.f};
      if (k < 2050) bv = *(const float4v*)&Wm[(size_t)k * 512 + lc];
      float a0 = ftile[tr * 4 + 0][kk];
      float a1 = ftile[tr * 4 + 1][kk];
      float a2 = ftile[tr * 4 + 2][kk];
      float a3 = ftile[tr * 4 + 3][kk];
#pragma unroll
      for (int j = 0; j < 4; j++){
        racc[0][j] += a0 * bv[j]; racc[1][j] += a1 * bv[j];
        racc[2][j] += a2 * bv[j]; racc[3][j] += a3 * bv[j];
      }
    }
    __syncthreads();
  }
#pragma unroll
  for (int i = 0; i < 4; i++){
    float4v v;
#pragma unroll
    for (int j = 0; j < 4; j++){
      float x = racc[i][j] + bm[lc + j];
      v[j] = fmaxf(x, 0.f);
    }
    *(float4v*)&G[(size_t)(r0 + tr * 4 + i) * 2048 + nbk * 64 + tc * 4] = v;
  }
}

__global__ void __launch_bounds__(256) final_q(const float* __restrict__ G,
    const float* __restrict__ head, const float* __restrict__ tq, const int* __restrict__ act,
    const float* __restrict__ Wsv, const float* __restrict__ bsv,
    const float* __restrict__ Wbv, const float* __restrict__ bbv,
    const float* __restrict__ Wsh, const float* __restrict__ bsh,
    const float* __restrict__ Wbh, const float* __restrict__ bbh,
    float* __restrict__ out){
  int row = blockIdx.x, tid = threadIdx.x;
  const float* g = G + (size_t)row * 2048;
  float s0=0,s1=0,s2=0,s3=0,s4=0,s5=0;
  for (int k = tid; k < 512; k += 256){
    float vlp = g[k], qlp = g[512 + k], vle = g[1024 + k], qle = g[1536 + k];
    s0 += vlp * Wsv[k];
    s1 += qlp * Wsh[2 * k];  s2 += qlp * Wsh[2 * k + 1];
    s3 += vle * Wbv[k];
    s4 += qle * Wbh[2 * k];  s5 += qle * Wbh[2 * k + 1];
  }
#pragma unroll
  for (int off = 32; off; off >>= 1){
    s0 += __shfl_down(s0, off); s1 += __shfl_down(s1, off); s2 += __shfl_down(s2, off);
    s3 += __shfl_down(s3, off); s4 += __shfl_down(s4, off); s5 += __shfl_down(s5, off);
  }
  __shared__ float red[4][6];
  int w = tid >> 6, lane = tid & 63;
  if (lane == 0){ red[w][0]=s0; red[w][1]=s1; red[w][2]=s2; red[w][3]=s3; red[w][4]=s4; red[w][5]=s5; }
  __syncthreads();
  if (tid == 0){
    float r[6];
#pragma unroll
    for (int i = 0; i < 6; i++) r[i] = red[0][i] + red[1][i] + red[2][i] + red[3][i];
    float pa0 = r[1] + bsh[0], pa1 = r[2] + bsh[1];
    float pv  = r[0] + bsv[0];
    float pm  = 0.5f * (pa0 + pa1);
    float pQ0 = pa0 - pm + pv, pQ1 = pa1 - pm + pv;
    float ea0 = r[4] + bbh[0], ea1 = r[5] + bbh[1];
    float ev  = r[3] + bbv[0];
    float em  = 0.5f * (ea0 + ea1);
    float eQ0 = ea0 - em + ev, eQ1 = ea1 - em + ev;
    bool isp = (head[row * 3] != 0.f);
    float Q0 = isp ? pQ0 : eQ0;
    float Q1 = isp ? eQ1 : pQ1;   // mask col1 = (1-is_pos)!=0
    float gr = (Q1 > Q0) ? 1.f : 0.f;
    int a = act[row];
    float iv = (a == 0) ? Q0 : Q1;
    float d = tq[row] - iv;
    atomicAdd(out, d * d * (1.f / 512.f));
    out[1 + 2 * row] = Q0;
    out[2 + 2 * row] = Q1;
    out[1025 + row] = gr;
  }
}

// ---------------- launch ----------------
extern "C" void kernel_launch(void* const* d_in, const int* in_sizes, int n_in,
                              void* d_out, int out_size, void* d_ws, size_t ws_size,
                              hipStream_t stream){
  const float* hist = (const float*)d_in[0];
  const float* head = (const float*)d_in[1];
  const float* tq   = (const float*)d_in[2];
  const int*   act  = (const int*)d_in[3];
  const float* Wl   = (const float*)d_in[4];
  const float* bl   = (const float*)d_in[5];
  const float* W3 = (const float*)d_in[6];  const float* b3 = (const float*)d_in[7];
  const float* W4 = (const float*)d_in[8];  const float* b4 = (const float*)d_in[9];
  const float* W5 = (const float*)d_in[10]; const float* b5 = (const float*)d_in[11];
  const float* W6 = (const float*)d_in[12]; const float* b6 = (const float*)d_in[13];
  const float* Wsv = (const float*)d_in[14]; const float* bsv = (const float*)d_in[15];
  const float* Wbv = (const float*)d_in[16]; const float* bbv = (const float*)d_in[17];
  const float* Wsh = (const float*)d_in[18]; const float* bsh = (const float*)d_in[19];
  const float* Wbh = (const float*)d_in[20]; const float* bbh = (const float*)d_in[21];
  float* out = (float*)d_out;

  char* ws = (char*)d_ws;
  unsigned* flags      = (unsigned*)ws;                       // 256*256*4 = 262144
  unsigned short* hp_hi = (unsigned short*)(ws + 262144);      // 2 MiB
  unsigned short* hp_lo = (unsigned short*)(ws + 2359296);     // 2 MiB
  unsigned short* wp    = (unsigned short*)(ws + 4456448);     // 18.87 MB
  float* cfin = (float*)(ws + 23330816);                       // 2 MiB
  float* feat = (float*)(ws + 25427968);                       // 4.26 MB
  float* G    = (float*)(ws + 29687808);                       // 4.19 MB -> total ~33.9 MB

  // opt in to >default dynamic LDS (144 KiB) for the persistent kernel
  static int lds_attr_set = 0;
  if (!lds_attr_set){
    hipFuncSetAttribute(reinterpret_cast<const void*>(lstm_coop),
                        hipFuncAttributeMaxDynamicSharedMemorySize, WLDS_BYTES);
    lds_attr_set = 1;
  }

  // zero barrier flags + both h double-buffers (h(-1) = 0)
  hipMemsetAsync(ws, 0, 4456448, stream);
  hipMemsetAsync(d_out, 0, sizeof(float), stream);             // loss accumulator

  pack_w<<<dim3(64 * 36), dim3(256), 0, stream>>>(Wl, wp);

  void* args[] = {(void*)&hist, (void*)&bl, (void*)&wp, (void*)&hp_hi,
                  (void*)&hp_lo, (void*)&cfin, (void*)&flags};
  hipError_t ce = hipLaunchCooperativeKernel((void*)lstm_coop, dim3(NBLK), dim3(512),
                                             args, WLDS_BYTES, stream);
  if (ce != hipSuccess){
    // fallback: plain launch. Co-residency is structural: 144 KiB LDS forces 1 block/CU
    // and grid == 256 == #CUs, so all blocks are resident; flag protocol needs no coop API.
    lstm_coop<<<dim3(NBLK), dim3(512), WLDS_BYTES, stream>>>(hist, bl, wp, hp_hi,
                                                             hp_lo, cfin, flags);
  }

  build_feat<<<dim3(512), dim3(256), 0, stream>>>(head, cfin, hp_hi, hp_lo, feat);
  mlp_head<<<dim3(256), dim3(256), 0, stream>>>(feat, W3, b3, W4, b4, W5, b5, W6, b6, G);
  final_q<<<dim3(512), dim3(256), 0, stream>>>(G, head, tq, act,
      Wsv, bsv, Wbv, bbv, Wsh, bsh, Wbh, bbh, out);
}

// Round 9
// 4990.685 us; speedup vs baseline: 1.6816x; 1.2720x over previous
//
#include <hip/hip_runtime.h>
#include <hip/hip_bf16.h>

#define B_ 512
#define T_ 256
#define F_ 128
#define H_ 1024
#define KD 1152          // F_ + H_
#define NBLK 256
#define HPBUF 524288     // elems per hpack buffer: 32 hseg * 512 rows * 32
#define WP_NB 147456     // elems per nb slice of packed W: 36 c32 * 8 frags * 512
#define WLDS_BYTES 147456  // dynamic LDS: W-hi resident, 36 c32 * 4 frags * 1 KiB

typedef __attribute__((ext_vector_type(8))) short short8;
typedef __attribute__((ext_vector_type(4))) float float4v;

#define MFMA(a,b,c) __builtin_amdgcn_mfma_f32_16x16x32_bf16(a,b,c,0,0,0)

__device__ __forceinline__ unsigned short f2bf(float x){
  unsigned u = __float_as_uint(x);
  unsigned r = (u + 0x7fffu + ((u >> 16) & 1u)) >> 16;
  return (unsigned short)r;
}
__device__ __forceinline__ float bf2f(unsigned short b){
  return __uint_as_float(((unsigned)b) << 16);
}
__device__ __forceinline__ float sigf(float x){ return 1.f / (1.f + __expf(-x)); }
__device__ __forceinline__ float tanh_f(float x){
  float e = __expf(2.f * x);
  return (e - 1.f) / (e + 1.f);
}

// async global->LDS copy, 16B per lane. lbase must be wave-uniform; HW adds lane*16.
__device__ __forceinline__ void cp16(const unsigned short* g, unsigned short* lbase, int lane){
#if defined(__has_builtin) && __has_builtin(__builtin_amdgcn_global_load_lds)
  __builtin_amdgcn_global_load_lds((const __attribute__((address_space(1))) unsigned int*)g,
                                   (__attribute__((address_space(3))) unsigned int*)lbase, 16, 0, 0);
#else
  *(short8*)(lbase + lane * 8) = *(const short8*)g;
#endif
}

// ---------------- W pre-pack: split hi/lo bf16 and lay out in MFMA B-fragment order -------------
// wp[nb][c32][frag 0..7][lane*8+j], frag 0..3 = hi for ntile(gate) 0..3, 4..7 = lo.
// (lo frags unused by the W-resident kernel; pack cost is one-time.)
__global__ void __launch_bounds__(256) pack_w(const float* __restrict__ Wl, unsigned short* __restrict__ wp){
  int bid = blockIdx.x;                 // 64*36
  int nb = bid / 36, c32 = bid % 36;
  int tid = threadIdx.x;
  int nt = tid >> 6, lane = tid & 63;
  int u = lane & 15, q = lane >> 4;
  int gcol = nt * H_ + nb * 16 + u;     // ntile == gate
  int k0 = c32 * 32 + q * 8;
  short8 hi, lo;
#pragma unroll
  for (int j = 0; j < 8; j++){
    float x = Wl[(size_t)(k0 + j) * 4096 + gcol];
    unsigned short hb = f2bf(x);
    hi[j] = (short)hb;
    lo[j] = (short)f2bf(x - bf2f(hb));
  }
  size_t base = (size_t)(nb * 36 + c32) * 8;
  *(short8*)&wp[(base + nt) * 512 + lane * 8] = hi;
  *(short8*)&wp[(base + 4 + nt) * 512 + lane * 8] = lo;
}

// ---------------- persistent cooperative LSTM kernel (W-resident in dynamic LDS) ----------------
// 256 blocks (1/CU), 512 threads (8 waves, 2/SIMD). Block = (nb, mb): nb 0..63 (16 N-cols),
// mb 0..3 (128 rows). Wave w owns rows rbase = mb*128 + w*16 (ONE 16-row m-tile), FULL K.
// W-hi (144 KiB) in LDS once. h carried as plain bf16 (hi only) -- A-path halved.
__device__ __forceinline__ void issueA(const unsigned short* __restrict__ rh,
                                       int aoff0, int c32, short8& d){
  d = *(const short8*)(rh + (c32 - 4) * 16384 + aoff0);
}

__device__ __forceinline__ void issueXF4(const float* __restrict__ xb0, int tn,
                                         float4v (&xf)[4][2]){
#pragma unroll
  for (int s = 0; s < 4; s++){
    const float* px = xb0 + tn * F_ + s * 32;
    xf[s][0] = *(const float4v*)px;
    xf[s][1] = *(const float4v*)(px + 4);
  }
}

// fb = &wlds[c32*2048 + lane*8]; 4 B-frag reads + 4 MFMA (A-hi x B-hi)
__device__ __forceinline__ void computeH(const unsigned short* fb, const short8& ah,
                                         float4v (&acc)[4]){
  short8 bh[4];
#pragma unroll
  for (int nt = 0; nt < 4; nt++) bh[nt] = *(const short8*)(fb + nt * 512);
#pragma unroll
  for (int nt = 0; nt < 4; nt++) acc[nt] = MFMA(ah, bh[nt], acc[nt]);
}

__device__ __forceinline__ void computeX4(const float4v (&xf)[4][2],
                                          const unsigned short* wl0,
                                          float4v (&acc)[4]){
#pragma unroll
  for (int s = 0; s < 4; s++){
    short8 hi8, lo8;
#pragma unroll
    for (int j = 0; j < 8; j++){
      float x = (j < 4) ? xf[s][0][j] : xf[s][1][j - 4];
      unsigned short hb = f2bf(x);
      hi8[j] = (short)hb;
      lo8[j] = (short)f2bf(x - bf2f(hb));
    }
    short8 bh[4];
#pragma unroll
    for (int nt = 0; nt < 4; nt++) bh[nt] = *(const short8*)(wl0 + s * 2048 + nt * 512);
#pragma unroll
    for (int nt = 0; nt < 4; nt++) acc[nt] = MFMA(hi8, bh[nt], acc[nt]);
#pragma unroll
    for (int nt = 0; nt < 4; nt++) acc[nt] = MFMA(lo8, bh[nt], acc[nt]);
  }
}

__global__ void __launch_bounds__(512, 2) lstm_coop(
    const float* __restrict__ hist, const float* __restrict__ blstm,
    const unsigned short* __restrict__ wp,
    unsigned short* __restrict__ hp_hi,
    float* __restrict__ cfin, unsigned* __restrict__ flags){
  extern __shared__ __align__(16) unsigned short wlds[];   // 144 KiB W-hi, resident all steps

  int b = blockIdx.x;
  int xcd = b & 7, jj = b >> 3;
  int nb = xcd * 8 + (jj & 7);          // XCD-local nb for L2 locality
  int mb = jj >> 3;                     // 0..3 ; 128-row group = barrier group
  int tid = threadIdx.x;
  int w = tid >> 6, lane = tid & 63;    // 8 waves, wave w owns rows rbase..rbase+15
  int u = lane & 15, q = lane >> 4;
  int rbase = mb * 128 + w * 16;

  const unsigned short* wp_nb = wp + (size_t)nb * WP_NB;

  // ---- one-time: W-hi -> LDS (144 frags of 1 KiB; wave w takes i = w, w+8, ...) ----
  for (int i = w; i < 144; i += 8)
    cp16(wp_nb + (size_t)((i >> 2) * 8 + (i & 3)) * 512 + lane * 8, &wlds[i * 512], lane);

  float bias_v[4];
#pragma unroll
  for (int nt = 0; nt < 4; nt++) bias_v[nt] = blstm[nt * H_ + nb * 16 + u];

  int rowA0 = rbase + u;                       // A-fragment rows (16-row tile)
  int aoff0 = rowA0 * 32 + q * 8;              // elems; + hseg*16384
  const float* xb0 = hist + (size_t)rowA0 * (T_ * F_) + q * 8;

  // h write offsets (C/D layout: unit = lane&15, row = q*4 + r)
  int hsegw = nb >> 1;
  int kin = (nb & 1) * 16 + u;
  int howbase = hsegw * 16384 + (rbase + q * 4) * 32 + kin;

  float cst[4];
#pragma unroll
  for (int r = 0; r < 4; r++) cst[r] = 0.f;

  float4v xf[4][2];
  issueXF4(xb0, 0, xf);
  __syncthreads();                             // W-hi staged (barrier drains vmcnt)

#pragma unroll 1
  for (int t = 0; t < T_; ++t){
    int bufr = t & 1, bufw = bufr ^ 1;
    const unsigned short* rh = hp_hi + bufr * HPBUF;

    float4v acc[4];
#pragma unroll
    for (int nt = 0; nt < 4; nt++) acc[nt] = (float4v){0.f, 0.f, 0.f, 0.f};

    // ---- x-part (no h dependency); wave0 polls the group barrier meanwhile ----
    computeX4(xf, wlds + lane * 8, acc);
    if (t && w == 0){
      const unsigned* f = flags + t * NBLK + (mb << 6);    // own 64-block group
      int ok;
      do {
        ok = (__hip_atomic_load(&f[lane], __ATOMIC_RELAXED, __HIP_MEMORY_SCOPE_AGENT) != 0u);
        if (__all(ok)) break;
        __builtin_amdgcn_s_sleep(2);
      } while (1);
      __builtin_amdgcn_fence(__ATOMIC_ACQUIRE, "agent");   // L2 inv before any h(t-1) read
    }
    __syncthreads();                                       // all waves ordered after fence

    // ---- h loop: full K per wave, A register-prefetched 8 c32 ahead ----
    short8 A0, A1, A2, A3, A4, A5, A6, A7;
    issueA(rh, aoff0,  4, A0); issueA(rh, aoff0,  5, A1);
    issueA(rh, aoff0,  6, A2); issueA(rh, aoff0,  7, A3);
    issueA(rh, aoff0,  8, A4); issueA(rh, aoff0,  9, A5);
    issueA(rh, aoff0, 10, A6); issueA(rh, aoff0, 11, A7);
#pragma unroll 1
    for (int c = 4; c < 28; c += 8){
      computeH(&wlds[(c + 0) * 2048 + lane * 8], A0, acc); issueA(rh, aoff0, c +  8, A0);
      computeH(&wlds[(c + 1) * 2048 + lane * 8], A1, acc); issueA(rh, aoff0, c +  9, A1);
      computeH(&wlds[(c + 2) * 2048 + lane * 8], A2, acc); issueA(rh, aoff0, c + 10, A2);
      computeH(&wlds[(c + 3) * 2048 + lane * 8], A3, acc); issueA(rh, aoff0, c + 11, A3);
      computeH(&wlds[(c + 4) * 2048 + lane * 8], A4, acc); issueA(rh, aoff0, c + 12, A4);
      computeH(&wlds[(c + 5) * 2048 + lane * 8], A5, acc); issueA(rh, aoff0, c + 13, A5);
      computeH(&wlds[(c + 6) * 2048 + lane * 8], A6, acc); issueA(rh, aoff0, c + 14, A6);
      computeH(&wlds[(c + 7) * 2048 + lane * 8], A7, acc); issueA(rh, aoff0, c + 15, A7);
    }
    // last group (c32 28..35), overlap x(t+1) prefetch
    issueXF4(xb0, (t + 1 < T_) ? t + 1 : t, xf);
    computeH(&wlds[28 * 2048 + lane * 8], A0, acc);
    computeH(&wlds[29 * 2048 + lane * 8], A1, acc);
    computeH(&wlds[30 * 2048 + lane * 8], A2, acc);
    computeH(&wlds[31 * 2048 + lane * 8], A3, acc);
    computeH(&wlds[32 * 2048 + lane * 8], A4, acc);
    computeH(&wlds[33 * 2048 + lane * 8], A5, acc);
    computeH(&wlds[34 * 2048 + lane * 8], A6, acc);
    computeH(&wlds[35 * 2048 + lane * 8], A7, acc);

    // ---- gate update (fully wave-local: this wave owns all 4 gates of its 16 rows) ----
    unsigned short* wh = hp_hi + bufw * HPBUF;
#pragma unroll
    for (int r = 0; r < 4; r++){
      float zi = acc[0][r] + bias_v[0];
      float zj = acc[1][r] + bias_v[1];
      float zf = acc[2][r] + bias_v[2];
      float zo = acc[3][r] + bias_v[3];
      float co = cst[r];
      float cn = sigf(zf + 1.f) * co + sigf(zi) * tanh_f(zj);
      float hn = sigf(zo) * tanh_f(cn);
      cst[r] = cn;
      wh[howbase + r * 32] = f2bf(hn);
      if (t == T_ - 1){
        int row = rbase + q * 4 + r;
        cfin[(size_t)row * H_ + nb * 16 + u] = cn;
      }
    }
    __syncthreads();                           // drains vmcnt: h stores complete at L2
    if (tid == 0 && t + 1 < T_){
      __builtin_amdgcn_fence(__ATOMIC_RELEASE, "agent");   // push h to coherence point
      __hip_atomic_store(&flags[(t + 1) * NBLK + b], 1u, __ATOMIC_RELAXED,
                         __HIP_MEMORY_SCOPE_AGENT);        // arrive for step t+1
    }
  }
}

// ---------------- head ----------------
__global__ void __launch_bounds__(256) build_feat(const float* __restrict__ head,
    const float* __restrict__ cfin, const unsigned short* __restrict__ hh,
    float* __restrict__ feat){
  int row = blockIdx.x;
  for (int kp = threadIdx.x; kp < 2080; kp += 256){
    float v;
    if (kp < 2) v = head[row * 3 + 1 + kp];
    else if (kp < 1026) v = cfin[(size_t)row * H_ + (kp - 2)];
    else if (kp < 2050){
      int n = kp - 1026;
      int off = (n >> 5) * 16384 + row * 32 + ((n & 31) >> 3) * 8 + (n & 7);
      v = bf2f(hh[off]);
    } else v = 0.f;
    feat[(size_t)row * 2080 + kp] = v;
  }
}

__global__ void __launch_bounds__(256) mlp_head(const float* __restrict__ feat,
    const float* __restrict__ W3, const float* __restrict__ b3,
    const float* __restrict__ W4, const float* __restrict__ b4,
    const float* __restrict__ W5, const float* __restrict__ b5,
    const float* __restrict__ W6, const float* __restrict__ b6,
    float* __restrict__ G){
  __shared__ float ftile[64][33];
  int bid = blockIdx.x;
  int mb = bid >> 5, nbk = bid & 31;
  int tid = threadIdx.x;
  int tr = tid >> 4, tc = tid & 15;
  int mat = nbk >> 3;
  const float* Wm = (mat == 0) ? W3 : (mat == 1) ? W4 : (mat == 2) ? W5 : W6;
  const float* bm = (mat == 0) ? b3 : (mat == 1) ? b4 : (mat == 2) ? b5 : b6;
  int lc = (nbk & 7) * 64 + tc * 4;
  int r0 = mb * 64;
  float racc[4][4] = {};
  for (int k0 = 0; k0 < 2080; k0 += 32){
    int rr = tid >> 3, cc = (tid & 7) * 4;
    float4v v0 = *(const float4v*)&feat[(size_t)(r0 + rr) * 2080 + k0 + cc];
    float4v v1 = *(const float4v*)&feat[(size_t)(r0 + rr + 32) * 2080 + k0 + cc];
#pragma unroll
    for (int i = 0; i < 4; i++){ ftile[rr][cc + i] = v0[i]; ftile[rr + 32][cc + i] = v1[i]; }
    __syncthreads();
#pragma unroll 4
    for (int kk = 0; kk < 32; kk++){
      int k = k0 + kk;
      float4v bv = (float4v){0.f, 0.f, 0.f, 0.f};
      if (k < 2050) bv = *(const float4v*)&Wm[(size_t)k * 512 + lc];
      float a0 = ftile[tr * 4 + 0][kk];
      float a1 = ftile[tr * 4 + 1][kk];
      float a2 = ftile[tr * 4 + 2][kk];
      float a3 = ftile[tr * 4 + 3][kk];
#pragma unroll
      for (int j = 0; j < 4; j++){
        racc[0][j] += a0 * bv[j]; racc[1][j] += a1 * bv[j];
        racc[2][j] += a2 * bv[j]; racc[3][j] += a3 * bv[j];
      }
    }
    __syncthreads();
  }
#pragma unroll
  for (int i = 0; i < 4; i++){
    float4v v;
#pragma unroll
    for (int j = 0; j < 4; j++){
      float x = racc[i][j] + bm[lc + j];
      v[j] = fmaxf(x, 0.f);
    }
    *(float4v*)&G[(size_t)(r0 + tr * 4 + i) * 2048 + nbk * 64 + tc * 4] = v;
  }
}

__global__ void __launch_bounds__(256) final_q(const float* __restrict__ G,
    const float* __restrict__ head, const float* __restrict__ tq, const int* __restrict__ act,
    const float* __restrict__ Wsv, const float* __restrict__ bsv,
    const float* __restrict__ Wbv, const float* __restrict__ bbv,
    const float* __restrict__ Wsh, const float* __restrict__ bsh,
    const float* __restrict__ Wbh, const float* __restrict__ bbh,
    float* __restrict__ out){
  int row = blockIdx.x, tid = threadIdx.x;
  const float* g = G + (size_t)row * 2048;
  float s0=0,s1=0,s2=0,s3=0,s4=0,s5=0;
  for (int k = tid; k < 512; k += 256){
    float vlp = g[k], qlp = g[512 + k], vle = g[1024 + k], qle = g[1536 + k];
    s0 += vlp * Wsv[k];
    s1 += qlp * Wsh[2 * k];  s2 += qlp * Wsh[2 * k + 1];
    s3 += vle * Wbv[k];
    s4 += qle * Wbh[2 * k];  s5 += qle * Wbh[2 * k + 1];
  }
#pragma unroll
  for (int off = 32; off; off >>= 1){
    s0 += __shfl_down(s0, off); s1 += __shfl_down(s1, off); s2 += __shfl_down(s2, off);
    s3 += __shfl_down(s3, off); s4 += __shfl_down(s4, off); s5 += __shfl_down(s5, off);
  }
  __shared__ float red[4][6];
  int w = tid >> 6, lane = tid & 63;
  if (lane == 0){ red[w][0]=s0; red[w][1]=s1; red[w][2]=s2; red[w][3]=s3; red[w][4]=s4; red[w][5]=s5; }
  __syncthreads();
  if (tid == 0){
    float r[6];
#pragma unroll
    for (int i = 0; i < 6; i++) r[i] = red[0][i] + red[1][i] + red[2][i] + red[3][i];
    float pa0 = r[1] + bsh[0], pa1 = r[2] + bsh[1];
    float pv  = r[0] + bsv[0];
    float pm  = 0.5f * (pa0 + pa1);
    float pQ0 = pa0 - pm + pv, pQ1 = pa1 - pm + pv;
    float ea0 = r[4] + bbh[0], ea1 = r[5] + bbh[1];
    float ev  = r[3] + bbv[0];
    float em  = 0.5f * (ea0 + ea1);
    float eQ0 = ea0 - em + ev, eQ1 = ea1 - em + ev;
    bool isp = (head[row * 3] != 0.f);
    float Q0 = isp ? pQ0 : eQ0;
    float Q1 = isp ? eQ1 : pQ1;   // mask col1 = (1-is_pos)!=0
    float gr = (Q1 > Q0) ? 1.f : 0.f;
    int a = act[row];
    float iv = (a == 0) ? Q0 : Q1;
    float d = tq[row] - iv;
    atomicAdd(out, d * d * (1.f / 512.f));
    out[1 + 2 * row] = Q0;
    out[2 + 2 * row] = Q1;
    out[1025 + row] = gr;
  }
}

// ---------------- launch ----------------
extern "C" void kernel_launch(void* const* d_in, const int* in_sizes, int n_in,
                              void* d_out, int out_size, void* d_ws, size_t ws_size,
                              hipStream_t stream){
  const float* hist = (const float*)d_in[0];
  const float* head = (const float*)d_in[1];
  const float* tq   = (const float*)d_in[2];
  const int*   act  = (const int*)d_in[3];
  const float* Wl   = (const float*)d_in[4];
  const float* bl   = (const float*)d_in[5];
  const float* W3 = (const float*)d_in[6];  const float* b3 = (const float*)d_in[7];
  const float* W4 = (const float*)d_in[8];  const float* b4 = (const float*)d_in[9];
  const float* W5 = (const float*)d_in[10]; const float* b5 = (const float*)d_in[11];
  const float* W6 = (const float*)d_in[12]; const float* b6 = (const float*)d_in[13];
  const float* Wsv = (const float*)d_in[14]; const float* bsv = (const float*)d_in[15];
  const float* Wbv = (const float*)d_in[16]; const float* bbv = (const float*)d_in[17];
  const float* Wsh = (const float*)d_in[18]; const float* bsh = (const float*)d_in[19];
  const float* Wbh = (const float*)d_in[20]; const float* bbh = (const float*)d_in[21];
  float* out = (float*)d_out;

  char* ws = (char*)d_ws;
  unsigned* flags      = (unsigned*)ws;                       // 256*256*4 = 262144
  unsigned short* hp_hi = (unsigned short*)(ws + 262144);      // 2 MiB (double buffer)
  unsigned short* wp    = (unsigned short*)(ws + 4456448);     // 18.87 MB (hole at old hp_lo kept)
  float* cfin = (float*)(ws + 23330816);                       // 2 MiB
  float* feat = (float*)(ws + 25427968);                       // 4.26 MB
  float* G    = (float*)(ws + 29687808);                       // 4.19 MB -> total ~33.9 MB

  // opt in to >default dynamic LDS (144 KiB) for the persistent kernel
  static int lds_attr_set = 0;
  if (!lds_attr_set){
    hipFuncSetAttribute(reinterpret_cast<const void*>(lstm_coop),
                        hipFuncAttributeMaxDynamicSharedMemorySize, WLDS_BYTES);
    lds_attr_set = 1;
  }

  // zero barrier flags + h double-buffer (h(-1) = 0)
  hipMemsetAsync(ws, 0, 2359296, stream);
  hipMemsetAsync(d_out, 0, sizeof(float), stream);             // loss accumulator

  pack_w<<<dim3(64 * 36), dim3(256), 0, stream>>>(Wl, wp);

  void* args[] = {(void*)&hist, (void*)&bl, (void*)&wp, (void*)&hp_hi,
                  (void*)&cfin, (void*)&flags};
  hipError_t ce = hipLaunchCooperativeKernel((void*)lstm_coop, dim3(NBLK), dim3(512),
                                             args, WLDS_BYTES, stream);
  if (ce != hipSuccess){
    // fallback: plain launch. Co-residency is structural: 144 KiB LDS forces 1 block/CU
    // and grid == 256 == #CUs, so all blocks are resident; flag protocol needs no coop API.
    lstm_coop<<<dim3(NBLK), dim3(512), WLDS_BYTES, stream>>>(hist, bl, wp, hp_hi,
                                                             cfin, flags);
  }

  build_feat<<<dim3(512), dim3(256), 0, stream>>>(head, cfin, hp_hi, feat);
  mlp_head<<<dim3(256), dim3(256), 0, stream>>>(feat, W3, b3, W4, b4, W5, b5, W6, b6, G);
  final_q<<<dim3(512), dim3(256), 0, stream>>>(G, head, tq, act,
      Wsv, bsv, Wbv, bbv, Wsh, bsh, Wbh, bbh, out);
}

// Round 10
// 2681.892 us; speedup vs baseline: 3.1292x; 1.8609x over previous
//
#include <hip/hip_runtime.h>
#include <hip/hip_bf16.h>

#define B_ 512
#define T_ 256
#define F_ 128
#define H_ 1024
#define KD 1152          // F_ + H_
#define NBLK 256
#define HPBUF 524288     // elems per hpack buffer: 32 hseg * 512 rows * 32
#define WP_NB 147456     // elems per nb slice of packed W: 36 c32 * 8 frags * 512
#define WLDS_BYTES 147456  // dynamic LDS: W-hi resident, 36 c32 * 4 frags * 1 KiB

typedef __attribute__((ext_vector_type(8))) short short8;
typedef __attribute__((ext_vector_type(4))) float float4v;

#define MFMA(a,b,c) __builtin_amdgcn_mfma_f32_16x16x32_bf16(a,b,c,0,0,0)

__device__ __forceinline__ unsigned short f2bf(float x){
  unsigned u = __float_as_uint(x);
  unsigned r = (u + 0x7fffu + ((u >> 16) & 1u)) >> 16;
  return (unsigned short)r;
}
__device__ __forceinline__ float bf2f(unsigned short b){
  return __uint_as_float(((unsigned)b) << 16);
}
__device__ __forceinline__ float sigf(float x){ return 1.f / (1.f + __expf(-x)); }
__device__ __forceinline__ float tanh_f(float x){
  float e = __expf(2.f * x);
  return (e - 1.f) / (e + 1.f);
}

// write-through 2B store to the coherence point (LLC): h stores drain overlapped with
// compute instead of via a serial L2-writeback fence at the step boundary.
__device__ __forceinline__ void st2_sys(unsigned short* p, unsigned short v){
  __hip_atomic_store(p, v, __ATOMIC_RELAXED, __HIP_MEMORY_SCOPE_SYSTEM);
}

// async global->LDS copy, 16B per lane. lbase must be wave-uniform; HW adds lane*16.
__device__ __forceinline__ void cp16(const unsigned short* g, unsigned short* lbase, int lane){
#if defined(__has_builtin) && __has_builtin(__builtin_amdgcn_global_load_lds)
  __builtin_amdgcn_global_load_lds((const __attribute__((address_space(1))) unsigned int*)g,
                                   (__attribute__((address_space(3))) unsigned int*)lbase, 16, 0, 0);
#else
  *(short8*)(lbase + lane * 8) = *(const short8*)g;
#endif
}

// ---------------- W pre-pack: split hi/lo bf16 and lay out in MFMA B-fragment order -------------
// wp[nb][c32][frag 0..7][lane*8+j], frag 0..3 = hi for ntile(gate) 0..3, 4..7 = lo.
// (lo frags unused by the W-resident kernel; pack cost is one-time.)
__global__ void __launch_bounds__(256) pack_w(const float* __restrict__ Wl, unsigned short* __restrict__ wp){
  int bid = blockIdx.x;                 // 64*36
  int nb = bid / 36, c32 = bid % 36;
  int tid = threadIdx.x;
  int nt = tid >> 6, lane = tid & 63;
  int u = lane & 15, q = lane >> 4;
  int gcol = nt * H_ + nb * 16 + u;     // ntile == gate
  int k0 = c32 * 32 + q * 8;
  short8 hi, lo;
#pragma unroll
  for (int j = 0; j < 8; j++){
    float x = Wl[(size_t)(k0 + j) * 4096 + gcol];
    unsigned short hb = f2bf(x);
    hi[j] = (short)hb;
    lo[j] = (short)f2bf(x - bf2f(hb));
  }
  size_t base = (size_t)(nb * 36 + c32) * 8;
  *(short8*)&wp[(base + nt) * 512 + lane * 8] = hi;
  *(short8*)&wp[(base + 4 + nt) * 512 + lane * 8] = lo;
}

// ---------------- persistent cooperative LSTM kernel (W-resident in dynamic LDS) ----------------
// 256 blocks (1/CU), 512 threads (8 waves, 2/SIMD). Block = (nb, mb): nb 0..63 (16 N-cols),
// mb 0..3 (128 rows). Wave w owns rows rbase = mb*128 + w*16 (ONE 16-row m-tile), FULL K.
// W-hi (144 KiB) in LDS once. h carried as plain bf16 (hi only) -- A-path halved.
__device__ __forceinline__ void issueA(const unsigned short* __restrict__ rh,
                                       int aoff0, int c32, short8& d){
  d = *(const short8*)(rh + (c32 - 4) * 16384 + aoff0);
}

__device__ __forceinline__ void issueXF4(const float* __restrict__ xb0, int tn,
                                         float4v (&xf)[4][2]){
#pragma unroll
  for (int s = 0; s < 4; s++){
    const float* px = xb0 + tn * F_ + s * 32;
    xf[s][0] = *(const float4v*)px;
    xf[s][1] = *(const float4v*)(px + 4);
  }
}

// fb = &wlds[c32*2048 + lane*8]; 4 B-frag reads + 4 MFMA (A-hi x B-hi)
__device__ __forceinline__ void computeH(const unsigned short* fb, const short8& ah,
                                         float4v (&acc)[4]){
  short8 bh[4];
#pragma unroll
  for (int nt = 0; nt < 4; nt++) bh[nt] = *(const short8*)(fb + nt * 512);
#pragma unroll
  for (int nt = 0; nt < 4; nt++) acc[nt] = MFMA(ah, bh[nt], acc[nt]);
}

__device__ __forceinline__ void computeX4(const float4v (&xf)[4][2],
                                          const unsigned short* wl0,
                                          float4v (&acc)[4]){
#pragma unroll
  for (int s = 0; s < 4; s++){
    short8 hi8, lo8;
#pragma unroll
    for (int j = 0; j < 8; j++){
      float x = (j < 4) ? xf[s][0][j] : xf[s][1][j - 4];
      unsigned short hb = f2bf(x);
      hi8[j] = (short)hb;
      lo8[j] = (short)f2bf(x - bf2f(hb));
    }
    short8 bh[4];
#pragma unroll
    for (int nt = 0; nt < 4; nt++) bh[nt] = *(const short8*)(wl0 + s * 2048 + nt * 512);
#pragma unroll
    for (int nt = 0; nt < 4; nt++) acc[nt] = MFMA(hi8, bh[nt], acc[nt]);
#pragma unroll
    for (int nt = 0; nt < 4; nt++) acc[nt] = MFMA(lo8, bh[nt], acc[nt]);
  }
}

__global__ void __launch_bounds__(512, 2) lstm_coop(
    const float* __restrict__ hist, const float* __restrict__ blstm,
    const unsigned short* __restrict__ wp,
    unsigned short* __restrict__ hp_hi,
    float* __restrict__ cfin, unsigned* __restrict__ flags){
  extern __shared__ __align__(16) unsigned short wlds[];   // 144 KiB W-hi, resident all steps

  int b = blockIdx.x;
  int xcd = b & 7, jj = b >> 3;
  int nb = xcd * 8 + (jj & 7);          // XCD-local nb for L2 locality
  int mb = jj >> 3;                     // 0..3 ; 128-row group = barrier group
  int tid = threadIdx.x;
  int w = tid >> 6, lane = tid & 63;    // 8 waves, wave w owns rows rbase..rbase+15
  int u = lane & 15, q = lane >> 4;
  int rbase = mb * 128 + w * 16;

  const unsigned short* wp_nb = wp + (size_t)nb * WP_NB;

  // ---- one-time: W-hi -> LDS (144 frags of 1 KiB; wave w takes i = w, w+8, ...) ----
  for (int i = w; i < 144; i += 8)
    cp16(wp_nb + (size_t)((i >> 2) * 8 + (i & 3)) * 512 + lane * 8, &wlds[i * 512], lane);

  float bias_v[4];
#pragma unroll
  for (int nt = 0; nt < 4; nt++) bias_v[nt] = blstm[nt * H_ + nb * 16 + u];

  int rowA0 = rbase + u;                       // A-fragment rows (16-row tile)
  int aoff0 = rowA0 * 32 + q * 8;              // elems; + hseg*16384
  const float* xb0 = hist + (size_t)rowA0 * (T_ * F_) + q * 8;

  // h write offsets (C/D layout: unit = lane&15, row = q*4 + r)
  int hsegw = nb >> 1;
  int kin = (nb & 1) * 16 + u;
  int howbase = hsegw * 16384 + (rbase + q * 4) * 32 + kin;

  float cst[4];
#pragma unroll
  for (int r = 0; r < 4; r++) cst[r] = 0.f;

  float4v xf[4][2];
  issueXF4(xb0, 0, xf);
  __syncthreads();                             // W-hi staged (barrier drains vmcnt)

#pragma unroll 1
  for (int t = 0; t < T_; ++t){
    int bufr = t & 1, bufw = bufr ^ 1;
    const unsigned short* rh = hp_hi + bufr * HPBUF;

    float4v acc[4];
#pragma unroll
    for (int nt = 0; nt < 4; nt++) acc[nt] = (float4v){0.f, 0.f, 0.f, 0.f};

    // ---- x-part (no h dependency); wave0 polls the group barrier meanwhile ----
    computeX4(xf, wlds + lane * 8, acc);
    if (t && w == 0){
      const unsigned* f = flags + t * NBLK + (mb << 6);    // own 64-block group
      int ok;
      do {
        ok = (__hip_atomic_load(&f[lane], __ATOMIC_RELAXED, __HIP_MEMORY_SCOPE_AGENT) != 0u);
        if (__all(ok)) break;
        __builtin_amdgcn_s_sleep(2);
      } while (1);
      __builtin_amdgcn_fence(__ATOMIC_ACQUIRE, "agent");   // L2 inv before any h(t-1) read
    }
    __syncthreads();                                       // all waves ordered after fence

    // ---- h loop: full K per wave, A register-prefetched 8 c32 ahead ----
    short8 A0, A1, A2, A3, A4, A5, A6, A7;
    issueA(rh, aoff0,  4, A0); issueA(rh, aoff0,  5, A1);
    issueA(rh, aoff0,  6, A2); issueA(rh, aoff0,  7, A3);
    issueA(rh, aoff0,  8, A4); issueA(rh, aoff0,  9, A5);
    issueA(rh, aoff0, 10, A6); issueA(rh, aoff0, 11, A7);
#pragma unroll 1
    for (int c = 4; c < 28; c += 8){
      computeH(&wlds[(c + 0) * 2048 + lane * 8], A0, acc); issueA(rh, aoff0, c +  8, A0);
      computeH(&wlds[(c + 1) * 2048 + lane * 8], A1, acc); issueA(rh, aoff0, c +  9, A1);
      computeH(&wlds[(c + 2) * 2048 + lane * 8], A2, acc); issueA(rh, aoff0, c + 10, A2);
      computeH(&wlds[(c + 3) * 2048 + lane * 8], A3, acc); issueA(rh, aoff0, c + 11, A3);
      computeH(&wlds[(c + 4) * 2048 + lane * 8], A4, acc); issueA(rh, aoff0, c + 12, A4);
      computeH(&wlds[(c + 5) * 2048 + lane * 8], A5, acc); issueA(rh, aoff0, c + 13, A5);
      computeH(&wlds[(c + 6) * 2048 + lane * 8], A6, acc); issueA(rh, aoff0, c + 14, A6);
      computeH(&wlds[(c + 7) * 2048 + lane * 8], A7, acc); issueA(rh, aoff0, c + 15, A7);
    }
    // last group (c32 28..35), overlap x(t+1) prefetch
    issueXF4(xb0, (t + 1 < T_) ? t + 1 : t, xf);
    computeH(&wlds[28 * 2048 + lane * 8], A0, acc);
    computeH(&wlds[29 * 2048 + lane * 8], A1, acc);
    computeH(&wlds[30 * 2048 + lane * 8], A2, acc);
    computeH(&wlds[31 * 2048 + lane * 8], A3, acc);
    computeH(&wlds[32 * 2048 + lane * 8], A4, acc);
    computeH(&wlds[33 * 2048 + lane * 8], A5, acc);
    computeH(&wlds[34 * 2048 + lane * 8], A6, acc);
    computeH(&wlds[35 * 2048 + lane * 8], A7, acc);

    // ---- gate update (fully wave-local: this wave owns all 4 gates of its 16 rows) ----
    // h stores are write-through to LLC: they drain overlapped with this tail instead of
    // via a serial wbl2 release-fence at the step boundary.
    unsigned short* wh = hp_hi + bufw * HPBUF;
#pragma unroll
    for (int r = 0; r < 4; r++){
      float zi = acc[0][r] + bias_v[0];
      float zj = acc[1][r] + bias_v[1];
      float zf = acc[2][r] + bias_v[2];
      float zo = acc[3][r] + bias_v[3];
      float co = cst[r];
      float cn = sigf(zf + 1.f) * co + sigf(zi) * tanh_f(zj);
      float hn = sigf(zo) * tanh_f(cn);
      cst[r] = cn;
      st2_sys(&wh[howbase + r * 32], f2bf(hn));
      if (t == T_ - 1){
        int row = rbase + q * 4 + r;
        cfin[(size_t)row * H_ + nb * 16 + u] = cn;
      }
    }
    __syncthreads();                           // drains vmcnt: h stores complete at LLC
    if (tid == 0 && t + 1 < T_){
      // no release fence needed: write-through stores are already at the coherence
      // point once vmcnt is drained; agent-scope flag store orders after them.
      __hip_atomic_store(&flags[(t + 1) * NBLK + b], 1u, __ATOMIC_RELAXED,
                         __HIP_MEMORY_SCOPE_AGENT);        // arrive for step t+1
    }
  }
}

// ---------------- head ----------------
__global__ void __launch_bounds__(256) build_feat(const float* __restrict__ head,
    const float* __restrict__ cfin, const unsigned short* __restrict__ hh,
    float* __restrict__ feat){
  int row = blockIdx.x;
  for (int kp = threadIdx.x; kp < 2080; kp += 256){
    float v;
    if (kp < 2) v = head[row * 3 + 1 + kp];
    else if (kp < 1026) v = cfin[(size_t)row * H_ + (kp - 2)];
    else if (kp < 2050){
      int n = kp - 1026;
      int off = (n >> 5) * 16384 + row * 32 + ((n & 31) >> 3) * 8 + (n & 7);
      v = bf2f(hh[off]);
    } else v = 0.f;
    feat[(size_t)row * 2080 + kp] = v;
  }
}

__global__ void __launch_bounds__(256) mlp_head(const float* __restrict__ feat,
    const float* __restrict__ W3, const float* __restrict__ b3,
    const float* __restrict__ W4, const float* __restrict__ b4,
    const float* __restrict__ W5, const float* __restrict__ b5,
    const float* __restrict__ W6, const float* __restrict__ b6,
    float* __restrict__ G){
  __shared__ float ftile[64][33];
  int bid = blockIdx.x;
  int mb = bid >> 5, nbk = bid & 31;
  int tid = threadIdx.x;
  int tr = tid >> 4, tc = tid & 15;
  int mat = nbk >> 3;
  const float* Wm = (mat == 0) ? W3 : (mat == 1) ? W4 : (mat == 2) ? W5 : W6;
  const float* bm = (mat == 0) ? b3 : (mat == 1) ? b4 : (mat == 2) ? b5 : b6;
  int lc = (nbk & 7) * 64 + tc * 4;
  int r0 = mb * 64;
  float racc[4][4] = {};
  for (int k0 = 0; k0 < 2080; k0 += 32){
    int rr = tid >> 3, cc = (tid & 7) * 4;
    float4v v0 = *(const float4v*)&feat[(size_t)(r0 + rr) * 2080 + k0 + cc];
    float4v v1 = *(const float4v*)&feat[(size_t)(r0 + rr + 32) * 2080 + k0 + cc];
#pragma unroll
    for (int i = 0; i < 4; i++){ ftile[rr][cc + i] = v0[i]; ftile[rr + 32][cc + i] = v1[i]; }
    __syncthreads();
#pragma unroll 4
    for (int kk = 0; kk < 32; kk++){
      int k = k0 + kk;
      float4v bv = (float4v){0.f, 0.f, 0.f, 0.f};
      if (k < 2050) bv = *(const float4v*)&Wm[(size_t)k * 512 + lc];
      float a0 = ftile[tr * 4 + 0][kk];
      float a1 = ftile[tr * 4 + 1][kk];
      float a2 = ftile[tr * 4 + 2][kk];
      float a3 = ftile[tr * 4 + 3][kk];
#pragma unroll
      for (int j = 0; j < 4; j++){
        racc[0][j] += a0 * bv[j]; racc[1][j] += a1 * bv[j];
        racc[2][j] += a2 * bv[j]; racc[3][j] += a3 * bv[j];
      }
    }
    __syncthreads();
  }
#pragma unroll
  for (int i = 0; i < 4; i++){
    float4v v;
#pragma unroll
    for (int j = 0; j < 4; j++){
      float x = racc[i][j] + bm[lc + j];
      v[j] = fmaxf(x, 0.f);
    }
    *(float4v*)&G[(size_t)(r0 + tr * 4 + i) * 2048 + nbk * 64 + tc * 4] = v;
  }
}

__global__ void __launch_bounds__(256) final_q(const float* __restrict__ G,
    const float* __restrict__ head, const float* __restrict__ tq, const int* __restrict__ act,
    const float* __restrict__ Wsv, const float* __restrict__ bsv,
    const float* __restrict__ Wbv, const float* __restrict__ bbv,
    const float* __restrict__ Wsh, const float* __restrict__ bsh,
    const float* __restrict__ Wbh, const float* __restrict__ bbh,
    float* __restrict__ out){
  int row = blockIdx.x, tid = threadIdx.x;
  const float* g = G + (size_t)row * 2048;
  float s0=0,s1=0,s2=0,s3=0,s4=0,s5=0;
  for (int k = tid; k < 512; k += 256){
    float vlp = g[k], qlp = g[512 + k], vle = g[1024 + k], qle = g[1536 + k];
    s0 += vlp * Wsv[k];
    s1 += qlp * Wsh[2 * k];  s2 += qlp * Wsh[2 * k + 1];
    s3 += vle * Wbv[k];
    s4 += qle * Wbh[2 * k];  s5 += qle * Wbh[2 * k + 1];
  }
#pragma unroll
  for (int off = 32; off; off >>= 1){
    s0 += __shfl_down(s0, off); s1 += __shfl_down(s1, off); s2 += __shfl_down(s2, off);
    s3 += __shfl_down(s3, off); s4 += __shfl_down(s4, off); s5 += __shfl_down(s5, off);
  }
  __shared__ float red[4][6];
  int w = tid >> 6, lane = tid & 63;
  if (lane == 0){ red[w][0]=s0; red[w][1]=s1; red[w][2]=s2; red[w][3]=s3; red[w][4]=s4; red[w][5]=s5; }
  __syncthreads();
  if (tid == 0){
    float r[6];
#pragma unroll
    for (int i = 0; i < 6; i++) r[i] = red[0][i] + red[1][i] + red[2][i] + red[3][i];
    float pa0 = r[1] + bsh[0], pa1 = r[2] + bsh[1];
    float pv  = r[0] + bsv[0];
    float pm  = 0.5f * (pa0 + pa1);
    float pQ0 = pa0 - pm + pv, pQ1 = pa1 - pm + pv;
    float ea0 = r[4] + bbh[0], ea1 = r[5] + bbh[1];
    float ev  = r[3] + bbv[0];
    float em  = 0.5f * (ea0 + ea1);
    float eQ0 = ea0 - em + ev, eQ1 = ea1 - em + ev;
    bool isp = (head[row * 3] != 0.f);
    float Q0 = isp ? pQ0 : eQ0;
    float Q1 = isp ? eQ1 : pQ1;   // mask col1 = (1-is_pos)!=0
    float gr = (Q1 > Q0) ? 1.f : 0.f;
    int a = act[row];
    float iv = (a == 0) ? Q0 : Q1;
    float d = tq[row] - iv;
    atomicAdd(out, d * d * (1.f / 512.f));
    out[1 + 2 * row] = Q0;
    out[2 + 2 * row] = Q1;
    out[1025 + row] = gr;
  }
}

// ---------------- launch ----------------
extern "C" void kernel_launch(void* const* d_in, const int* in_sizes, int n_in,
                              void* d_out, int out_size, void* d_ws, size_t ws_size,
                              hipStream_t stream){
  const float* hist = (const float*)d_in[0];
  const float* head = (const float*)d_in[1];
  const float* tq   = (const float*)d_in[2];
  const int*   act  = (const int*)d_in[3];
  const float* Wl   = (const float*)d_in[4];
  const float* bl   = (const float*)d_in[5];
  const float* W3 = (const float*)d_in[6];  const float* b3 = (const float*)d_in[7];
  const float* W4 = (const float*)d_in[8];  const float* b4 = (const float*)d_in[9];
  const float* W5 = (const float*)d_in[10]; const float* b5 = (const float*)d_in[11];
  const float* W6 = (const float*)d_in[12]; const float* b6 = (const float*)d_in[13];
  const float* Wsv = (const float*)d_in[14]; const float* bsv = (const float*)d_in[15];
  const float* Wbv = (const float*)d_in[16]; const float* bbv = (const float*)d_in[17];
  const float* Wsh = (const float*)d_in[18]; const float* bsh = (const float*)d_in[19];
  const float* Wbh = (const float*)d_in[20]; const float* bbh = (const float*)d_in[21];
  float* out = (float*)d_out;

  char* ws = (char*)d_ws;
  unsigned* flags      = (unsigned*)ws;                       // 256*256*4 = 262144
  unsigned short* hp_hi = (unsigned short*)(ws + 262144);      // 2 MiB (double buffer)
  unsigned short* wp    = (unsigned short*)(ws + 4456448);     // 18.87 MB (hole at old hp_lo kept)
  float* cfin = (float*)(ws + 23330816);                       // 2 MiB
  float* feat = (float*)(ws + 25427968);                       // 4.26 MB
  float* G    = (float*)(ws + 29687808);                       // 4.19 MB -> total ~33.9 MB

  // opt in to >default dynamic LDS (144 KiB) for the persistent kernel
  static int lds_attr_set = 0;
  if (!lds_attr_set){
    hipFuncSetAttribute(reinterpret_cast<const void*>(lstm_coop),
                        hipFuncAttributeMaxDynamicSharedMemorySize, WLDS_BYTES);
    lds_attr_set = 1;
  }

  // zero barrier flags + h double-buffer (h(-1) = 0)
  hipMemsetAsync(ws, 0, 2359296, stream);
  hipMemsetAsync(d_out, 0, sizeof(float), stream);             // loss accumulator

  pack_w<<<dim3(64 * 36), dim3(256), 0, stream>>>(Wl, wp);

  void* args[] = {(void*)&hist, (void*)&bl, (void*)&wp, (void*)&hp_hi,
                  (void*)&cfin, (void*)&flags};
  hipError_t ce = hipLaunchCooperativeKernel((void*)lstm_coop, dim3(NBLK), dim3(512),
                                             args, WLDS_BYTES, stream);
  if (ce != hipSuccess){
    // fallback: plain launch. Co-residency is structural: 144 KiB LDS forces 1 block/CU
    // and grid == 256 == #CUs, so all blocks are resident; flag protocol needs no coop API.
    lstm_coop<<<dim3(NBLK), dim3(512), WLDS_BYTES, stream>>>(hist, bl, wp, hp_hi,
                                                             cfin, flags);
  }

  build_feat<<<dim3(512), dim3(256), 0, stream>>>(head, cfin, hp_hi, feat);
  mlp_head<<<dim3(256), dim3(256), 0, stream>>>(feat, W3, b3, W4, b4, W5, b5, W6, b6, G);
  final_q<<<dim3(512), dim3(256), 0, stream>>>(G, head, tq, act,
      Wsv, bsv, Wbv, bbv, Wsh, bsh, Wbh, bbh, out);
}